// Round 2
// baseline (2206.920 us; speedup 1.0000x reference)
//
#include <hip/hip_runtime.h>
#include <hip/hip_bf16.h>

#define BB 128
#define LL 128
#define DD 300
#define MDIM 50
#define GINDIM 350
#define HDIM 256     // per-direction hidden
#define G3 768       // 3*HDIM
#define HH 512       // ctx dim
#define RR 128
#define TT 4
#define NKB 4        // branches
#define MTOT (BB*LL) // 16384
#define N2 1536      // both dirs stacked gates

// ---------------- ws layout (bytes) ----------------
#define OFF_GI      0ull                          // [2][MTOT][768] bf16 = 50,331,648
#define OFF_CTX     50331648ull                   // [MTOT][512] f32   = 33,554,432
#define OFF_CK      83886080ull                   // [MTOT][512] f32   = 33,554,432
#define OFF_FK      117440512ull                  // [4][MTOT][4] f32  = 1,048,576
#define OFF_AL      118489088ull                  // [4][B][L][4] f32  = 1,048,576
#define OFF_SP      119537664ull                  // [4][B][L] f32     = 262,144
#define OFF_SPSUM   119799808ull                  // [4][B] f32        = 2,048
#define OFF_SV      119801856ull                  // [B][2048] f32     = 1,048,576
#define OFF_WIHT    120850432ull                  // [352][1536] f32   = 2,162,688
#define OFF_HWT     123013120ull                  // [512][512] f32    = 1,048,576
#define OFF_WHHT    124061696ull                  // [2][256][768] bf16= 786,432
#define OFF_BIAS    124848128ull                  // [1536] f32
#define OFF_HBALL   124854272ull                  // [512] f32
#define OFF_BEG     124856320ull                  // [128] int
#define OFF_TN      124856832ull                  // [128] int

__device__ __forceinline__ float sigf(float x) { return 1.f / (1.f + expf(-x)); }

// ---------------- prep kernels ----------------
__global__ __launch_bounds__(256) void k_zero_ctx(float4* p) {
    size_t n4 = (size_t)MTOT * HH / 4;
    for (size_t i = blockIdx.x * 256ull + threadIdx.x; i < n4; i += (size_t)gridDim.x * 256ull)
        p[i] = make_float4(0.f, 0.f, 0.f, 0.f);
}

__global__ __launch_bounds__(256) void k_prep_wih(const float* __restrict__ Wf,
        const float* __restrict__ Wb, const float* __restrict__ bf_,
        const float* __restrict__ bb_, float* __restrict__ WihT, float* __restrict__ biasAll) {
    int idx = blockIdx.x * 256 + threadIdx.x;
    if (idx < 352 * N2) {
        int kk = idx / N2, n = idx % N2;
        int dir = n >= G3; int g = n - dir * G3;
        const float* W = dir ? Wb : Wf;
        WihT[idx] = (kk < GINDIM) ? W[(size_t)g * GINDIM + kk] : 0.f;
    }
    if (idx < N2) biasAll[idx] = (idx < G3) ? bf_[idx] : bb_[idx - G3];
}

__global__ __launch_bounds__(256) void k_prep_hw(const float* __restrict__ hW,
        const float* __restrict__ hb, float* __restrict__ hWT, float* __restrict__ hbAll) {
    int idx = blockIdx.x * 256 + threadIdx.x;   // 512*512
    if (idx < HH * HH) {
        int h = idx >> 9, n = idx & 511;
        hWT[idx] = hW[(size_t)n * HH + h];
    }
    if (idx < HH) hbAll[idx] = hb[idx];
}

__global__ __launch_bounds__(256) void k_prep_whh(const float* __restrict__ Wf,
        const float* __restrict__ Wb, __hip_bfloat16* __restrict__ WhhT) {
    int idx = blockIdx.x * 256 + threadIdx.x;   // 2*256*768
    if (idx >= 2 * HDIM * G3) return;
    int dir = idx / (HDIM * G3); int rem = idx % (HDIM * G3);
    int j = rem / G3, g = rem % G3;
    const float* W = dir ? Wb : Wf;             // [768][256]
    WhhT[idx] = __float2bfloat16(W[(size_t)g * HDIM + j]);
}

__global__ __launch_bounds__(128) void k_prep_bt(const int* __restrict__ masks,
        int* __restrict__ beg, int* __restrict__ tn) {
    int b = threadIdx.x;
    int best = masks[b * LL]; int idx = 0; int s = 0;
    for (int j = 0; j < LL; ++j) {
        int v = masks[b * LL + j]; s += v;
        if (v > best) { best = v; idx = j; }
    }
    beg[b] = idx; tn[b] = s;
}

// ---------------- GEMM 1: gi = x @ WihT + bias, bf16 out ----------------
__global__ __launch_bounds__(256) void k_gemm_gi(const float* __restrict__ sents,
        const float* __restrict__ mask_table, const int* __restrict__ masks,
        const float* __restrict__ WihT, const float* __restrict__ biasAll,
        __hip_bfloat16* __restrict__ gi) {
    __shared__ float As[16][68];
    __shared__ float Bs[16][68];
    const int tid = threadIdx.x;
    const int m0 = blockIdx.y * 64;
    const int n0 = blockIdx.x * 64;
    const int tx = tid & 15, ty = tid >> 4;
    const int a_row = tid >> 2;
    const int a_k = (tid & 3) * 4;
    const int b_col = tid & 63;
    const int b_k0 = tid >> 6;
    const int m_glob = m0 + a_row;
    const int mask_v = masks[m_glob];
    const float* arow = sents + (size_t)m_glob * DD;
    const float* mrow = mask_table + mask_v * MDIM;
    float acc[4][4] = {};
    for (int k0 = 0; k0 < 352; k0 += 16) {
        #pragma unroll
        for (int i = 0; i < 4; ++i) {
            int k = k0 + a_k + i;
            float v = 0.f;
            if (k < GINDIM) v = (k < DD) ? arow[k] : mrow[k - DD];
            As[a_k + i][a_row] = v;
        }
        #pragma unroll
        for (int i = 0; i < 4; ++i) {
            int kk = b_k0 + i * 4;
            Bs[kk][b_col] = WihT[(size_t)(k0 + kk) * N2 + n0 + b_col];
        }
        __syncthreads();
        #pragma unroll
        for (int kk = 0; kk < 16; ++kk) {
            float a[4], bv[4];
            #pragma unroll
            for (int i = 0; i < 4; ++i) a[i] = As[kk][ty * 4 + i];
            #pragma unroll
            for (int j = 0; j < 4; ++j) bv[j] = Bs[kk][tx * 4 + j];
            #pragma unroll
            for (int i = 0; i < 4; ++i)
                #pragma unroll
                for (int j = 0; j < 4; ++j)
                    acc[i][j] += a[i] * bv[j];
        }
        __syncthreads();
    }
    #pragma unroll
    for (int i = 0; i < 4; ++i) {
        int m = m0 + ty * 4 + i;
        #pragma unroll
        for (int j = 0; j < 4; ++j) {
            int n = n0 + tx * 4 + j;
            float v = acc[i][j] + biasAll[n];
            int dir = n >= G3; int g = n - dir * G3;
            gi[((size_t)dir * MTOT + m) * G3 + g] = __float2bfloat16(v);
        }
    }
}

// ---------------- GEMM 2: ck = ctx @ hWT + hb ----------------
__global__ __launch_bounds__(256) void k_gemm_ck(const float* __restrict__ ctx,
        const float* __restrict__ hWT, const float* __restrict__ hbAll,
        float* __restrict__ ck) {
    __shared__ float As[16][68];
    __shared__ float Bs[16][68];
    const int tid = threadIdx.x;
    const int m0 = blockIdx.y * 64;
    const int n0 = blockIdx.x * 64;
    const int tx = tid & 15, ty = tid >> 4;
    const int a_row = tid >> 2;
    const int a_k = (tid & 3) * 4;
    const int b_col = tid & 63;
    const int b_k0 = tid >> 6;
    const float* arow = ctx + (size_t)(m0 + a_row) * HH;
    float acc[4][4] = {};
    for (int k0 = 0; k0 < HH; k0 += 16) {
        #pragma unroll
        for (int i = 0; i < 4; ++i)
            As[a_k + i][a_row] = arow[k0 + a_k + i];
        #pragma unroll
        for (int i = 0; i < 4; ++i) {
            int kk = b_k0 + i * 4;
            Bs[kk][b_col] = hWT[(size_t)(k0 + kk) * HH + n0 + b_col];
        }
        __syncthreads();
        #pragma unroll
        for (int kk = 0; kk < 16; ++kk) {
            float a[4], bv[4];
            #pragma unroll
            for (int i = 0; i < 4; ++i) a[i] = As[kk][ty * 4 + i];
            #pragma unroll
            for (int j = 0; j < 4; ++j) bv[j] = Bs[kk][tx * 4 + j];
            #pragma unroll
            for (int i = 0; i < 4; ++i)
                #pragma unroll
                for (int j = 0; j < 4; ++j)
                    acc[i][j] += a[i] * bv[j];
        }
        __syncthreads();
    }
    #pragma unroll
    for (int i = 0; i < 4; ++i) {
        int m = m0 + ty * 4 + i;
        #pragma unroll
        for (int j = 0; j < 4; ++j) {
            int n = n0 + tx * 4 + j;
            ck[(size_t)m * HH + n] = acc[i][j] + hbAll[n];
        }
    }
}

// ---------------- pos weight ----------------
__device__ __forceinline__ float poswt(int j, int beg, int tn, int len, float lf, int mv) {
    float w = (j < beg) ? (1.f - (float)(beg - j) / lf) : 0.f;
    if (mv == 1) w = 1.f;
    if (j > beg + tn) w = 1.f - (float)(j - beg) / lf;
    if (j > len) w = 0.f;
    return w;
}

// ---------------- GRU recurrence (one block per dir,batch) ----------------
__global__ __launch_bounds__(256) void k_gru(const __hip_bfloat16* __restrict__ gi,
        const __hip_bfloat16* __restrict__ WhhT,
        const float* __restrict__ gbhhf, const float* __restrict__ gbhhb,
        const int* __restrict__ lens, const int* __restrict__ masks,
        const int* __restrict__ beg_, const int* __restrict__ tn_,
        float* __restrict__ ctx) {
    __shared__ float hs[HDIM];
    const int e = threadIdx.x;
    const int bidx = blockIdx.x;
    const int dir = bidx >> 7;
    const int b = bidx & 127;
    const int len = lens[b];
    const int beg = beg_[b], tn = tn_[b];
    const float lf = (float)len;
    const float* bhh = dir ? gbhhb : gbhhf;
    const float bhr = bhh[e], bhz = bhh[HDIM + e], bhn = bhh[2 * HDIM + e];
    const __hip_bfloat16* WT = WhhT + (size_t)dir * HDIM * G3;
    const __hip_bfloat16* giD = gi + (size_t)dir * MTOT * G3;
    float h = 0.f;
    hs[e] = 0.f;
    __syncthreads();
    for (int l = 0; l < LL; ++l) {
        float ghr = 0.f, ghz = 0.f, ghn = 0.f;
        #pragma unroll 4
        for (int j = 0; j < HDIM; ++j) {
            float hj = hs[j];
            const __hip_bfloat16* w = WT + (size_t)j * G3;
            ghr += __bfloat162float(w[e]) * hj;
            ghz += __bfloat162float(w[HDIM + e]) * hj;
            ghn += __bfloat162float(w[2 * HDIM + e]) * hj;
        }
        const int tg = dir ? min(max(len - 1 - l, 0), LL - 1) : l;
        const __hip_bfloat16* grow = giD + (size_t)(b * LL + tg) * G3;
        const float gir = __bfloat162float(grow[e]);
        const float giz = __bfloat162float(grow[HDIM + e]);
        const float gin = __bfloat162float(grow[2 * HDIM + e]);
        const float rr = sigf(gir + ghr + bhr);
        const float zz = sigf(giz + ghz + bhz);
        const float nn = tanhf(gin + rr * (ghn + bhn));
        const float hnew = (1.f - zz) * nn + zz * h;
        const bool valid = l < len;
        __syncthreads();
        if (valid) { h = hnew; hs[e] = hnew; }
        __syncthreads();
        if (!dir) {
            const float y = valid ? hnew : 0.f;
            const float w = poswt(l, beg, tn, len, lf, masks[b * LL + l]);
            ctx[((size_t)(b * LL + l)) * HH + e] = y * w;
        } else if (valid) {
            const int jout = len - 1 - l;
            const float w = poswt(jout, beg, tn, len, lf, masks[b * LL + jout]);
            ctx[((size_t)(b * LL + jout)) * HH + HDIM + e] = hnew * w;
        }
    }
}

// ---------------- fk = ck_k @ tW_k^T + tb ----------------
__global__ __launch_bounds__(256) void k_fk(const float* __restrict__ ck,
        const float* __restrict__ tW, const float* __restrict__ tb,
        float* __restrict__ fk) {
    int gid = blockIdx.x * 256 + threadIdx.x;  // MTOT*16
    int m = gid >> 4;
    int kt = gid & 15;
    int k = kt >> 2, t = kt & 3;
    const float* c = ck + (size_t)m * HH + k * RR;
    const float* w = tW + (size_t)(k * TT + t) * RR;
    float acc = tb[k * TT + t];
    #pragma unroll 4
    for (int r = 0; r < RR; ++r) acc += c[r] * w[r];
    fk[((size_t)k * MTOT + m) * TT + t] = acc;
}

// ---------------- CRF forward/backward marginals (4 lanes per (k,b)) ----------------
__global__ __launch_bounds__(64) void k_crf(const float* __restrict__ fk,
        const float* __restrict__ trans, const int* __restrict__ lens,
        float* __restrict__ alphas, float* __restrict__ sp, float* __restrict__ spsum) {
    const int tid = blockIdx.x * 64 + threadIdx.x;   // 2048 total
    const int pid = tid >> 2;                        // 512 pairs
    const int t = tid & 3;
    const int k = pid >> 7, b = pid & 127;
    const int len = lens[b];
    const float* f = fk + ((size_t)k * MTOT + (size_t)b * LL) * TT;
    const float* tr = trans + k * 16;
    const float trC0 = tr[0 * 4 + t], trC1 = tr[1 * 4 + t], trC2 = tr[2 * 4 + t], trC3 = tr[3 * 4 + t];
    const float trR0 = tr[t * 4 + 0], trR1 = tr[t * 4 + 1], trR2 = tr[t * 4 + 2], trR3 = tr[t * 4 + 3];
    float* al = alphas + ((size_t)k * BB + b) * LL * TT;
    const int base = threadIdx.x & ~3;
    float alpha = f[t];
    al[t] = alpha;
    for (int l = 1; l < LL; ++l) {
        float a0 = __shfl(alpha, base + 0);
        float a1 = __shfl(alpha, base + 1);
        float a2 = __shfl(alpha, base + 2);
        float a3 = __shfl(alpha, base + 3);
        float v0 = a0 + trC0, v1 = a1 + trC1, v2 = a2 + trC2, v3 = a3 + trC3;
        float mx = fmaxf(fmaxf(v0, v1), fmaxf(v2, v3));
        float sum = expf(v0 - mx) + expf(v1 - mx) + expf(v2 - mx) + expf(v3 - mx);
        float nw = mx + logf(sum) + f[l * TT + t];
        if (l < len) alpha = nw;
        al[l * TT + t] = alpha;
    }
    float beta = 0.f;
    float ssum = 0.f;
    for (int l = LL - 1; l >= 0; --l) {
        if (l < LL - 1) {
            float fb = f[(l + 1) * TT + t] + beta;
            float c0 = __shfl(fb, base + 0);
            float c1 = __shfl(fb, base + 1);
            float c2 = __shfl(fb, base + 2);
            float c3 = __shfl(fb, base + 3);
            float w0 = trR0 + c0, w1 = trR1 + c1, w2 = trR2 + c2, w3 = trR3 + c3;
            float mx = fmaxf(fmaxf(w0, w1), fmaxf(w2, w3));
            float nb = mx + logf(expf(w0 - mx) + expf(w1 - mx) + expf(w2 - mx) + expf(w3 - mx));
            if (l + 1 < len) beta = nb;
        }
        float v = al[l * TT + t] + beta;
        float mx = fmaxf(v, __shfl_xor(v, 1));
        mx = fmaxf(mx, __shfl_xor(mx, 2));
        float p = expf(v - mx);
        float s = p;
        s += __shfl_xor(s, 1);
        s += __shfl_xor(s, 2);
        float m1 = __shfl(p, base + 1) / s;
        float spv = (l < len) ? m1 : 0.f;
        if (t == 0) sp[((size_t)k * BB + b) * LL + l] = spv;
        ssum += spv;
    }
    if (t == 0) spsum[k * BB + b] = ssum;
}

// ---------------- pooling: sv[b, k*512+h] ----------------
__global__ __launch_bounds__(256) void k_pool(const float* __restrict__ ctx,
        const float* __restrict__ sp, const float* __restrict__ spsum,
        float* __restrict__ sv) {
    __shared__ float s_sp[NKB][LL];
    __shared__ float s_inv[NKB];
    const int b = blockIdx.x;
    const int tid = threadIdx.x;
    for (int i = tid; i < NKB * LL; i += 256) {
        int k = i >> 7, l = i & 127;
        s_sp[k][l] = sp[((size_t)k * BB + b) * LL + l];
    }
    if (tid < NKB) s_inv[tid] = 1.f / spsum[tid * BB + b];
    __syncthreads();
    #pragma unroll
    for (int i = 0; i < 8; ++i) {
        int n = tid + i * 256;
        int k = n >> 9, h = n & 511;
        float acc = 0.f;
        for (int l = 0; l < LL; ++l)
            acc += s_sp[k][l] * ctx[((size_t)b * LL + l) * HH + h];
        sv[(size_t)b * 2048 + n] = acc * s_inv[k];
    }
}

// ---------------- final: scores, log-softmax, mean NLL (float32 out!) ----------------
__global__ __launch_bounds__(128) void k_final(const float* __restrict__ sv,
        const float* __restrict__ lW, const float* __restrict__ lb,
        const int* __restrict__ labels, float* __restrict__ out) {
    __shared__ float red[128];
    const int b = threadIdx.x;
    float s0 = lb[0], s1 = lb[1], s2 = lb[2];
    const float* svb = sv + (size_t)b * 2048;
    for (int hh = 0; hh < 2048; ++hh) {
        float v = fmaxf(svb[hh], 0.f);
        s0 += v * lW[0 * 2048 + hh];
        s1 += v * lW[1 * 2048 + hh];
        s2 += v * lW[2 * 2048 + hh];
    }
    float mx = fmaxf(s0, fmaxf(s1, s2));
    float lse = mx + logf(expf(s0 - mx) + expf(s1 - mx) + expf(s2 - mx));
    int lab = labels[b];
    float sc = lab == 0 ? s0 : (lab == 1 ? s1 : s2);
    red[b] = lse - sc;
    __syncthreads();
    for (int st = 64; st > 0; st >>= 1) {
        if (b < st) red[b] += red[b + st];
        __syncthreads();
    }
    if (b == 0) out[0] = red[0] * (1.f / 128.f);
}

extern "C" void kernel_launch(void* const* d_in, const int* in_sizes, int n_in,
                              void* d_out, int out_size, void* d_ws, size_t ws_size,
                              hipStream_t stream) {
    const float* sents      = (const float*)d_in[0];
    const float* mask_table = (const float*)d_in[1];
    const float* gWihf      = (const float*)d_in[2];
    const float* gWhhf      = (const float*)d_in[3];
    const float* gbihf      = (const float*)d_in[4];
    const float* gbhhf      = (const float*)d_in[5];
    const float* gWihb      = (const float*)d_in[6];
    const float* gWhhb      = (const float*)d_in[7];
    const float* gbihb      = (const float*)d_in[8];
    const float* gbhhb      = (const float*)d_in[9];
    const float* hW         = (const float*)d_in[10];
    const float* hb         = (const float*)d_in[11];
    const float* tW         = (const float*)d_in[12];
    const float* tb         = (const float*)d_in[13];
    const float* trans      = (const float*)d_in[14];
    const float* lW         = (const float*)d_in[15];
    const float* lb         = (const float*)d_in[16];
    const int*   masks      = (const int*)d_in[17];
    const int*   lens       = (const int*)d_in[18];
    const int*   labels     = (const int*)d_in[19];

    char* wsb = (char*)d_ws;
    __hip_bfloat16* gi    = (__hip_bfloat16*)(wsb + OFF_GI);
    float* ctx            = (float*)(wsb + OFF_CTX);
    float* ck             = (float*)(wsb + OFF_CK);
    float* fk             = (float*)(wsb + OFF_FK);
    float* alphas         = (float*)(wsb + OFF_AL);
    float* sp             = (float*)(wsb + OFF_SP);
    float* spsum          = (float*)(wsb + OFF_SPSUM);
    float* sv             = (float*)(wsb + OFF_SV);
    float* WihT           = (float*)(wsb + OFF_WIHT);
    float* hWT            = (float*)(wsb + OFF_HWT);
    __hip_bfloat16* WhhT  = (__hip_bfloat16*)(wsb + OFF_WHHT);
    float* biasAll        = (float*)(wsb + OFF_BIAS);
    float* hbAll          = (float*)(wsb + OFF_HBALL);
    int* beg              = (int*)(wsb + OFF_BEG);
    int* tn               = (int*)(wsb + OFF_TN);

    hipLaunchKernelGGL(k_zero_ctx, dim3(2048), dim3(256), 0, stream, (float4*)ctx);
    hipLaunchKernelGGL(k_prep_wih, dim3((352 * N2 + 255) / 256), dim3(256), 0, stream,
                       gWihf, gWihb, gbihf, gbihb, WihT, biasAll);
    hipLaunchKernelGGL(k_prep_hw, dim3((HH * HH + 255) / 256), dim3(256), 0, stream,
                       hW, hb, hWT, hbAll);
    hipLaunchKernelGGL(k_prep_whh, dim3((2 * HDIM * G3 + 255) / 256), dim3(256), 0, stream,
                       gWhhf, gWhhb, WhhT);
    hipLaunchKernelGGL(k_prep_bt, dim3(1), dim3(128), 0, stream, masks, beg, tn);

    hipLaunchKernelGGL(k_gemm_gi, dim3(N2 / 64, MTOT / 64), dim3(256), 0, stream,
                       sents, mask_table, masks, WihT, biasAll, gi);
    hipLaunchKernelGGL(k_gru, dim3(256), dim3(256), 0, stream,
                       gi, WhhT, gbhhf, gbhhb, lens, masks, beg, tn, ctx);
    hipLaunchKernelGGL(k_gemm_ck, dim3(HH / 64, MTOT / 64), dim3(256), 0, stream,
                       ctx, hWT, hbAll, ck);
    hipLaunchKernelGGL(k_fk, dim3(MTOT * 16 / 256), dim3(256), 0, stream, ck, tW, tb, fk);
    hipLaunchKernelGGL(k_crf, dim3(32), dim3(64), 0, stream, fk, trans, lens, alphas, sp, spsum);
    hipLaunchKernelGGL(k_pool, dim3(BB), dim3(256), 0, stream, ctx, sp, spsum, sv);
    hipLaunchKernelGGL(k_final, dim3(1), dim3(128), 0, stream, sv, lW, lb, labels, (float*)d_out);
}

// Round 3
// 1191.481 us; speedup vs baseline: 1.8522x; 1.8522x over previous
//
#include <hip/hip_runtime.h>
#include <hip/hip_bf16.h>

#define BB 128
#define LL 128
#define DD 300
#define MDIM 50
#define GINDIM 350
#define HDIM 256     // per-direction hidden
#define G3 768       // 3*HDIM
#define HH 512       // ctx dim
#define RR 128
#define TT 4
#define NKB 4        // branches
#define MTOT (BB*LL) // 16384
#define N2 1536      // both dirs stacked gates

// ---------------- ws layout (bytes) ----------------
#define OFF_GI      0ull                          // [2][MTOT][768] bf16 = 50,331,648
#define OFF_CTX     50331648ull                   // [MTOT][512] f32   = 33,554,432
#define OFF_CK      83886080ull                   // [MTOT][512] f32   = 33,554,432
#define OFF_FK      117440512ull                  // [4][MTOT][4] f32  = 1,048,576
#define OFF_AL      118489088ull                  // [4][B][L][4] f32  = 1,048,576
#define OFF_SP      119537664ull                  // [4][B][L] f32     = 262,144
#define OFF_SPSUM   119799808ull                  // [4][B] f32        = 2,048
#define OFF_SV      119801856ull                  // [B][2048] f32     = 1,048,576
#define OFF_WIHT    120850432ull                  // [352][1536] f32   = 2,162,688
#define OFF_HWT     123013120ull                  // [512][512] f32    = 1,048,576
#define OFF_WHHT    124061696ull                  // [2][32][768][8] bf16 = 786,432 (swizzled)
#define OFF_BIAS    124848128ull                  // [1536] f32
#define OFF_HBALL   124854272ull                  // [512] f32
#define OFF_BEG     124856320ull                  // [128] int
#define OFF_TN      124856832ull                  // [128] int
#define OFF_SCORES  124857344ull                  // [128][3] f32

__device__ __forceinline__ float sigf(float x) { return 1.f / (1.f + expf(-x)); }
__device__ __forceinline__ float blo(unsigned u) { return __uint_as_float(u << 16); }
__device__ __forceinline__ float bhi(unsigned u) { return __uint_as_float(u & 0xffff0000u); }

// ---------------- prep kernels ----------------
__global__ __launch_bounds__(256) void k_zero_ctx(float4* p) {
    size_t n4 = (size_t)MTOT * HH / 4;
    for (size_t i = blockIdx.x * 256ull + threadIdx.x; i < n4; i += (size_t)gridDim.x * 256ull)
        p[i] = make_float4(0.f, 0.f, 0.f, 0.f);
}

__global__ __launch_bounds__(256) void k_prep_wih(const float* __restrict__ Wf,
        const float* __restrict__ Wb, const float* __restrict__ bf_,
        const float* __restrict__ bb_, float* __restrict__ WihT, float* __restrict__ biasAll) {
    int idx = blockIdx.x * 256 + threadIdx.x;
    if (idx < 352 * N2) {
        int kk = idx / N2, n = idx % N2;
        int dir = n >= G3; int g = n - dir * G3;
        const float* W = dir ? Wb : Wf;
        WihT[idx] = (kk < GINDIM) ? W[(size_t)g * GINDIM + kk] : 0.f;
    }
    if (idx < N2) biasAll[idx] = (idx < G3) ? bf_[idx] : bb_[idx - G3];
}

__global__ __launch_bounds__(256) void k_prep_hw(const float* __restrict__ hW,
        const float* __restrict__ hb, float* __restrict__ hWT, float* __restrict__ hbAll) {
    int idx = blockIdx.x * 256 + threadIdx.x;   // 512*512
    if (idx < HH * HH) {
        int h = idx >> 9, n = idx & 511;
        hWT[idx] = hW[(size_t)n * HH + h];
    }
    if (idx < HH) hbAll[idx] = hb[idx];
}

// Wt[dir][jc(32)][g(768)][jj(8)] bf16 : thread g reads contiguous 16B, coalesced across g
__global__ __launch_bounds__(256) void k_prep_whh(const float* __restrict__ Wf,
        const float* __restrict__ Wb, __hip_bfloat16* __restrict__ Wt) {
    int idx = blockIdx.x * 256 + threadIdx.x;   // 2*768*256
    if (idx >= 2 * G3 * HDIM) return;
    int dir = idx / (G3 * HDIM); int rem = idx % (G3 * HDIM);
    int g = rem / HDIM, j = rem % HDIM;
    const float* W = dir ? Wb : Wf;             // [768][256]
    int jc = j >> 3, jj = j & 7;
    Wt[(((size_t)dir * 32 + jc) * G3 + g) * 8 + jj] = __float2bfloat16(W[(size_t)g * HDIM + j]);
}

__global__ __launch_bounds__(128) void k_prep_bt(const int* __restrict__ masks,
        int* __restrict__ beg, int* __restrict__ tn) {
    int b = threadIdx.x;
    int best = masks[b * LL]; int idx = 0; int s = 0;
    for (int j = 0; j < LL; ++j) {
        int v = masks[b * LL + j]; s += v;
        if (v > best) { best = v; idx = j; }
    }
    beg[b] = idx; tn[b] = s;
}

// ---------------- GEMM 1: gi = x @ WihT + bias, bf16 out ----------------
__global__ __launch_bounds__(256) void k_gemm_gi(const float* __restrict__ sents,
        const float* __restrict__ mask_table, const int* __restrict__ masks,
        const float* __restrict__ WihT, const float* __restrict__ biasAll,
        __hip_bfloat16* __restrict__ gi) {
    __shared__ float As[16][68];
    __shared__ float Bs[16][68];
    const int tid = threadIdx.x;
    const int m0 = blockIdx.y * 64;
    const int n0 = blockIdx.x * 64;
    const int tx = tid & 15, ty = tid >> 4;
    const int a_row = tid >> 2;
    const int a_k = (tid & 3) * 4;
    const int b_col = tid & 63;
    const int b_k0 = tid >> 6;
    const int m_glob = m0 + a_row;
    const int mask_v = masks[m_glob];
    const float* arow = sents + (size_t)m_glob * DD;
    const float* mrow = mask_table + mask_v * MDIM;
    float acc[4][4] = {};
    for (int k0 = 0; k0 < 352; k0 += 16) {
        #pragma unroll
        for (int i = 0; i < 4; ++i) {
            int k = k0 + a_k + i;
            float v = 0.f;
            if (k < GINDIM) v = (k < DD) ? arow[k] : mrow[k - DD];
            As[a_k + i][a_row] = v;
        }
        #pragma unroll
        for (int i = 0; i < 4; ++i) {
            int kk = b_k0 + i * 4;
            Bs[kk][b_col] = WihT[(size_t)(k0 + kk) * N2 + n0 + b_col];
        }
        __syncthreads();
        #pragma unroll
        for (int kk = 0; kk < 16; ++kk) {
            float a[4], bv[4];
            #pragma unroll
            for (int i = 0; i < 4; ++i) a[i] = As[kk][ty * 4 + i];
            #pragma unroll
            for (int j = 0; j < 4; ++j) bv[j] = Bs[kk][tx * 4 + j];
            #pragma unroll
            for (int i = 0; i < 4; ++i)
                #pragma unroll
                for (int j = 0; j < 4; ++j)
                    acc[i][j] += a[i] * bv[j];
        }
        __syncthreads();
    }
    #pragma unroll
    for (int i = 0; i < 4; ++i) {
        int m = m0 + ty * 4 + i;
        #pragma unroll
        for (int j = 0; j < 4; ++j) {
            int n = n0 + tx * 4 + j;
            float v = acc[i][j] + biasAll[n];
            int dir = n >= G3; int g = n - dir * G3;
            gi[((size_t)dir * MTOT + m) * G3 + g] = __float2bfloat16(v);
        }
    }
}

// ---------------- GEMM 2: ck = ctx @ hWT + hb ----------------
__global__ __launch_bounds__(256) void k_gemm_ck(const float* __restrict__ ctx,
        const float* __restrict__ hWT, const float* __restrict__ hbAll,
        float* __restrict__ ck) {
    __shared__ float As[16][68];
    __shared__ float Bs[16][68];
    const int tid = threadIdx.x;
    const int m0 = blockIdx.y * 64;
    const int n0 = blockIdx.x * 64;
    const int tx = tid & 15, ty = tid >> 4;
    const int a_row = tid >> 2;
    const int a_k = (tid & 3) * 4;
    const int b_col = tid & 63;
    const int b_k0 = tid >> 6;
    const float* arow = ctx + (size_t)(m0 + a_row) * HH;
    float acc[4][4] = {};
    for (int k0 = 0; k0 < HH; k0 += 16) {
        #pragma unroll
        for (int i = 0; i < 4; ++i)
            As[a_k + i][a_row] = arow[k0 + a_k + i];
        #pragma unroll
        for (int i = 0; i < 4; ++i) {
            int kk = b_k0 + i * 4;
            Bs[kk][b_col] = hWT[(size_t)(k0 + kk) * HH + n0 + b_col];
        }
        __syncthreads();
        #pragma unroll
        for (int kk = 0; kk < 16; ++kk) {
            float a[4], bv[4];
            #pragma unroll
            for (int i = 0; i < 4; ++i) a[i] = As[kk][ty * 4 + i];
            #pragma unroll
            for (int j = 0; j < 4; ++j) bv[j] = Bs[kk][tx * 4 + j];
            #pragma unroll
            for (int i = 0; i < 4; ++i)
                #pragma unroll
                for (int j = 0; j < 4; ++j)
                    acc[i][j] += a[i] * bv[j];
        }
        __syncthreads();
    }
    #pragma unroll
    for (int i = 0; i < 4; ++i) {
        int m = m0 + ty * 4 + i;
        #pragma unroll
        for (int j = 0; j < 4; ++j) {
            int n = n0 + tx * 4 + j;
            ck[(size_t)m * HH + n] = acc[i][j] + hbAll[n];
        }
    }
}

// ---------------- pos weight ----------------
__device__ __forceinline__ float poswt(int j, int beg, int tn, int len, float lf, int mv) {
    float w = (j < beg) ? (1.f - (float)(beg - j) / lf) : 0.f;
    if (mv == 1) w = 1.f;
    if (j > beg + tn) w = 1.f - (float)(j - beg) / lf;
    if (j > len) w = 0.f;
    return w;
}

// ---------------- GRU recurrence: 1 block per (dir,batch), 768 threads ----------------
// Thread g computes gate row g (dot over K=256); nonlinearity by threads g<256.
__global__ __launch_bounds__(768) void k_gru(const __hip_bfloat16* __restrict__ gi,
        const __hip_bfloat16* __restrict__ Wt,
        const float* __restrict__ gbhhf, const float* __restrict__ gbhhb,
        const int* __restrict__ lens, const int* __restrict__ masks,
        const int* __restrict__ beg_, const int* __restrict__ tn_,
        float* __restrict__ ctx) {
    __shared__ float hs[HDIM];        // current hidden (f32)
    __shared__ float s_pre[G3];       // gate pre-activations
    __shared__ float s_gin[HDIM];     // input-side n gate
    const int g = threadIdx.x;
    const int bidx = blockIdx.x;
    const int dir = bidx >> 7;
    const int b = bidx & 127;
    const int len = lens[b];
    const int beg = beg_[b], tn = tn_[b];
    const float lf = (float)len;
    const float bhh_g = (dir ? gbhhb : gbhhf)[g];
    const __hip_bfloat16* giD = gi + (size_t)dir * MTOT * G3;
    const uint4* __restrict__ wp = (const uint4*)Wt + (size_t)dir * 32 * G3 + g;
    const float4* hs4 = (const float4*)hs;
    const size_t base_m = (size_t)b * LL;

    float hval = 0.f;
    if (g < HDIM) hs[g] = 0.f;
    __syncthreads();

    for (int l = 0; l < len; ++l) {
        const int pos = dir ? (len - 1 - l) : l;   // gi row AND output position
        float acc = 0.f;
        #pragma unroll 8
        for (int jc = 0; jc < 32; ++jc) {
            uint4 w = wp[(size_t)jc * G3];
            float4 ha = hs4[2 * jc];
            float4 hbv = hs4[2 * jc + 1];
            acc = fmaf(blo(w.x), ha.x, acc);  acc = fmaf(bhi(w.x), ha.y, acc);
            acc = fmaf(blo(w.y), ha.z, acc);  acc = fmaf(bhi(w.y), ha.w, acc);
            acc = fmaf(blo(w.z), hbv.x, acc); acc = fmaf(bhi(w.z), hbv.y, acc);
            acc = fmaf(blo(w.w), hbv.z, acc); acc = fmaf(bhi(w.w), hbv.w, acc);
        }
        float pre = acc + bhh_g;
        float giv = __bfloat162float(giD[(base_m + pos) * G3 + g]);
        if (g < 2 * HDIM) {
            s_pre[g] = pre + giv;        // r, z: input + hidden side
        } else {
            s_pre[g] = pre;              // n hidden side (ghn + bhn)
            s_gin[g - 2 * HDIM] = giv;   // n input side
        }
        __syncthreads();                  // dots done (hs reads complete) + LDS visible
        if (g < HDIM) {
            float r = sigf(s_pre[g]);
            float z = sigf(s_pre[HDIM + g]);
            float n = tanhf(s_gin[g] + r * s_pre[2 * HDIM + g]);
            float hnew = (1.f - z) * n + z * hval;
            hval = hnew;
            hs[g] = hnew;
            float w = poswt(pos, beg, tn, len, lf, masks[b * LL + pos]);
            ctx[(base_m + pos) * HH + dir * HDIM + g] = hnew * w;
        }
        __syncthreads();                  // hs update visible before next dot
    }
}

// ---------------- fk = ck_k @ tW_k^T + tb ----------------
__global__ __launch_bounds__(256) void k_fk(const float* __restrict__ ck,
        const float* __restrict__ tW, const float* __restrict__ tb,
        float* __restrict__ fk) {
    int gid = blockIdx.x * 256 + threadIdx.x;  // MTOT*16
    int m = gid >> 4;
    int kt = gid & 15;
    int k = kt >> 2, t = kt & 3;
    const float* c = ck + (size_t)m * HH + k * RR;
    const float* w = tW + (size_t)(k * TT + t) * RR;
    float acc = tb[k * TT + t];
    #pragma unroll 4
    for (int r = 0; r < RR; ++r) acc += c[r] * w[r];
    fk[((size_t)k * MTOT + m) * TT + t] = acc;
}

// ---------------- CRF forward/backward marginals (4 lanes per (k,b)) ----------------
__global__ __launch_bounds__(64) void k_crf(const float* __restrict__ fk,
        const float* __restrict__ trans, const int* __restrict__ lens,
        float* __restrict__ alphas, float* __restrict__ sp, float* __restrict__ spsum) {
    const int tid = blockIdx.x * 64 + threadIdx.x;   // 2048 total
    const int pid = tid >> 2;                        // 512 pairs
    const int t = tid & 3;
    const int k = pid >> 7, b = pid & 127;
    const int len = lens[b];
    const float* f = fk + ((size_t)k * MTOT + (size_t)b * LL) * TT;
    const float* tr = trans + k * 16;
    const float trC0 = tr[0 * 4 + t], trC1 = tr[1 * 4 + t], trC2 = tr[2 * 4 + t], trC3 = tr[3 * 4 + t];
    const float trR0 = tr[t * 4 + 0], trR1 = tr[t * 4 + 1], trR2 = tr[t * 4 + 2], trR3 = tr[t * 4 + 3];
    float* al = alphas + ((size_t)k * BB + b) * LL * TT;
    const int base = threadIdx.x & ~3;
    float alpha = f[t];
    al[t] = alpha;
    for (int l = 1; l < LL; ++l) {
        float a0 = __shfl(alpha, base + 0);
        float a1 = __shfl(alpha, base + 1);
        float a2 = __shfl(alpha, base + 2);
        float a3 = __shfl(alpha, base + 3);
        float v0 = a0 + trC0, v1 = a1 + trC1, v2 = a2 + trC2, v3 = a3 + trC3;
        float mx = fmaxf(fmaxf(v0, v1), fmaxf(v2, v3));
        float sum = expf(v0 - mx) + expf(v1 - mx) + expf(v2 - mx) + expf(v3 - mx);
        float nw = mx + logf(sum) + f[l * TT + t];
        if (l < len) alpha = nw;
        al[l * TT + t] = alpha;
    }
    float beta = 0.f;
    float ssum = 0.f;
    for (int l = LL - 1; l >= 0; --l) {
        if (l < LL - 1) {
            float fb = f[(l + 1) * TT + t] + beta;
            float c0 = __shfl(fb, base + 0);
            float c1 = __shfl(fb, base + 1);
            float c2 = __shfl(fb, base + 2);
            float c3 = __shfl(fb, base + 3);
            float w0 = trR0 + c0, w1 = trR1 + c1, w2 = trR2 + c2, w3 = trR3 + c3;
            float mx = fmaxf(fmaxf(w0, w1), fmaxf(w2, w3));
            float nb = mx + logf(expf(w0 - mx) + expf(w1 - mx) + expf(w2 - mx) + expf(w3 - mx));
            if (l + 1 < len) beta = nb;
        }
        float v = al[l * TT + t] + beta;
        float mx = fmaxf(v, __shfl_xor(v, 1));
        mx = fmaxf(mx, __shfl_xor(mx, 2));
        float p = expf(v - mx);
        float s = p;
        s += __shfl_xor(s, 1);
        s += __shfl_xor(s, 2);
        float m1 = __shfl(p, base + 1) / s;
        float spv = (l < len) ? m1 : 0.f;
        if (t == 0) sp[((size_t)k * BB + b) * LL + l] = spv;
        ssum += spv;
    }
    if (t == 0) spsum[k * BB + b] = ssum;
}

// ---------------- pooling: sv[b, k*512+h] ----------------
__global__ __launch_bounds__(256) void k_pool(const float* __restrict__ ctx,
        const float* __restrict__ sp, const float* __restrict__ spsum,
        float* __restrict__ sv) {
    __shared__ float s_sp[NKB][LL];
    __shared__ float s_inv[NKB];
    const int b = blockIdx.x;
    const int tid = threadIdx.x;
    for (int i = tid; i < NKB * LL; i += 256) {
        int k = i >> 7, l = i & 127;
        s_sp[k][l] = sp[((size_t)k * BB + b) * LL + l];
    }
    if (tid < NKB) s_inv[tid] = 1.f / spsum[tid * BB + b];
    __syncthreads();
    #pragma unroll
    for (int i = 0; i < 8; ++i) {
        int n = tid + i * 256;
        int k = n >> 9, h = n & 511;
        float acc = 0.f;
        for (int l = 0; l < LL; ++l)
            acc += s_sp[k][l] * ctx[((size_t)b * LL + l) * HH + h];
        sv[(size_t)b * 2048 + n] = acc * s_inv[k];
    }
}

// ---------------- scores[b][3] = relu(sv[b]) @ lW^T + lb ----------------
__global__ __launch_bounds__(256) void k_scores(const float* __restrict__ sv,
        const float* __restrict__ lW, const float* __restrict__ lb,
        float* __restrict__ scores) {
    __shared__ float red[3][4];
    const int b = blockIdx.x;
    const int tid = threadIdx.x;
    const float* svb = sv + (size_t)b * 2048;
    float a0 = 0.f, a1 = 0.f, a2 = 0.f;
    for (int i = tid; i < 2048; i += 256) {
        float v = fmaxf(svb[i], 0.f);
        a0 += v * lW[i];
        a1 += v * lW[2048 + i];
        a2 += v * lW[4096 + i];
    }
    #pragma unroll
    for (int off = 32; off > 0; off >>= 1) {
        a0 += __shfl_down(a0, off);
        a1 += __shfl_down(a1, off);
        a2 += __shfl_down(a2, off);
    }
    const int wid = tid >> 6, lane = tid & 63;
    if (lane == 0) { red[0][wid] = a0; red[1][wid] = a1; red[2][wid] = a2; }
    __syncthreads();
    if (tid < 3) {
        scores[b * 3 + tid] = red[tid][0] + red[tid][1] + red[tid][2] + red[tid][3] + lb[tid];
    }
}

// ---------------- final: log-softmax + mean NLL (float32 out) ----------------
__global__ __launch_bounds__(128) void k_final2(const float* __restrict__ scores,
        const int* __restrict__ labels, float* __restrict__ out) {
    __shared__ float red[128];
    const int b = threadIdx.x;
    float s0 = scores[b * 3 + 0], s1 = scores[b * 3 + 1], s2 = scores[b * 3 + 2];
    float mx = fmaxf(s0, fmaxf(s1, s2));
    float lse = mx + logf(expf(s0 - mx) + expf(s1 - mx) + expf(s2 - mx));
    int lab = labels[b];
    float sc = lab == 0 ? s0 : (lab == 1 ? s1 : s2);
    red[b] = lse - sc;
    __syncthreads();
    for (int st = 64; st > 0; st >>= 1) {
        if (b < st) red[b] += red[b + st];
        __syncthreads();
    }
    if (b == 0) out[0] = red[0] * (1.f / 128.f);
}

extern "C" void kernel_launch(void* const* d_in, const int* in_sizes, int n_in,
                              void* d_out, int out_size, void* d_ws, size_t ws_size,
                              hipStream_t stream) {
    const float* sents      = (const float*)d_in[0];
    const float* mask_table = (const float*)d_in[1];
    const float* gWihf      = (const float*)d_in[2];
    const float* gWhhf      = (const float*)d_in[3];
    const float* gbihf      = (const float*)d_in[4];
    const float* gbhhf      = (const float*)d_in[5];
    const float* gWihb      = (const float*)d_in[6];
    const float* gWhhb      = (const float*)d_in[7];
    const float* gbihb      = (const float*)d_in[8];
    const float* gbhhb      = (const float*)d_in[9];
    const float* hW         = (const float*)d_in[10];
    const float* hb         = (const float*)d_in[11];
    const float* tW         = (const float*)d_in[12];
    const float* tb         = (const float*)d_in[13];
    const float* trans      = (const float*)d_in[14];
    const float* lW         = (const float*)d_in[15];
    const float* lb         = (const float*)d_in[16];
    const int*   masks      = (const int*)d_in[17];
    const int*   lens       = (const int*)d_in[18];
    const int*   labels     = (const int*)d_in[19];

    char* wsb = (char*)d_ws;
    __hip_bfloat16* gi    = (__hip_bfloat16*)(wsb + OFF_GI);
    float* ctx            = (float*)(wsb + OFF_CTX);
    float* ck             = (float*)(wsb + OFF_CK);
    float* fk             = (float*)(wsb + OFF_FK);
    float* alphas         = (float*)(wsb + OFF_AL);
    float* sp             = (float*)(wsb + OFF_SP);
    float* spsum          = (float*)(wsb + OFF_SPSUM);
    float* sv             = (float*)(wsb + OFF_SV);
    float* WihT           = (float*)(wsb + OFF_WIHT);
    float* hWT            = (float*)(wsb + OFF_HWT);
    __hip_bfloat16* Wt    = (__hip_bfloat16*)(wsb + OFF_WHHT);
    float* biasAll        = (float*)(wsb + OFF_BIAS);
    float* hbAll          = (float*)(wsb + OFF_HBALL);
    int* beg              = (int*)(wsb + OFF_BEG);
    int* tn               = (int*)(wsb + OFF_TN);
    float* scores         = (float*)(wsb + OFF_SCORES);

    hipLaunchKernelGGL(k_zero_ctx, dim3(2048), dim3(256), 0, stream, (float4*)ctx);
    hipLaunchKernelGGL(k_prep_wih, dim3((352 * N2 + 255) / 256), dim3(256), 0, stream,
                       gWihf, gWihb, gbihf, gbihb, WihT, biasAll);
    hipLaunchKernelGGL(k_prep_hw, dim3((HH * HH + 255) / 256), dim3(256), 0, stream,
                       hW, hb, hWT, hbAll);
    hipLaunchKernelGGL(k_prep_whh, dim3((2 * G3 * HDIM + 255) / 256), dim3(256), 0, stream,
                       gWhhf, gWhhb, Wt);
    hipLaunchKernelGGL(k_prep_bt, dim3(1), dim3(128), 0, stream, masks, beg, tn);

    hipLaunchKernelGGL(k_gemm_gi, dim3(N2 / 64, MTOT / 64), dim3(256), 0, stream,
                       sents, mask_table, masks, WihT, biasAll, gi);
    hipLaunchKernelGGL(k_gru, dim3(256), dim3(768), 0, stream,
                       gi, (const __hip_bfloat16*)Wt, gbhhf, gbhhb, lens, masks, beg, tn, ctx);
    hipLaunchKernelGGL(k_gemm_ck, dim3(HH / 64, MTOT / 64), dim3(256), 0, stream,
                       ctx, hWT, hbAll, ck);
    hipLaunchKernelGGL(k_fk, dim3(MTOT * 16 / 256), dim3(256), 0, stream, ck, tW, tb, fk);
    hipLaunchKernelGGL(k_crf, dim3(32), dim3(64), 0, stream, fk, trans, lens, alphas, sp, spsum);
    hipLaunchKernelGGL(k_pool, dim3(BB), dim3(256), 0, stream, ctx, sp, spsum, sv);
    hipLaunchKernelGGL(k_scores, dim3(BB), dim3(256), 0, stream, sv, lW, lb, scores);
    hipLaunchKernelGGL(k_final2, dim3(1), dim3(128), 0, stream, scores, labels, (float*)d_out);
}

// Round 4
// 1095.341 us; speedup vs baseline: 2.0148x; 1.0878x over previous
//
#include <hip/hip_runtime.h>
#include <hip/hip_bf16.h>

#define BB 128
#define LL 128
#define DD 300
#define MDIM 50
#define GINDIM 350
#define HDIM 256     // per-direction hidden
#define G3 768       // 3*HDIM
#define HH 512       // ctx dim
#define RR 128
#define TT 4
#define NKB 4        // branches
#define MTOT (BB*LL) // 16384
#define N2 1536      // both dirs stacked gates
#define KP 352       // padded GRU-input K

typedef __attribute__((ext_vector_type(8))) short short8;
typedef __attribute__((ext_vector_type(4))) float f32x4;

// ---------------- ws layout (bytes) ----------------
#define OFF_GI      0ull            // gi bf16 [2][16384][768] = 50,331,648 ; reused later for ck f32 [16384][512]
#define OFF_CK      0ull
#define OFF_CTX     50331648ull     // f32 [16384][512]  = 33,554,432
#define OFF_CTXB    83886080ull     // bf16 [16384][512] = 16,777,216
#define OFF_XBF     100663296ull    // bf16 [16384][352] = 11,534,336
#define OFF_WIHB    112197632ull    // bf16 [1536][352]  = 1,081,344
#define OFF_HWB     113278976ull    // bf16 [512][512]   = 524,288
#define OFF_WHHB    113803264ull    // bf16 [2][768][256]= 786,432
#define OFF_BIAS    114589696ull    // f32 [1536]
#define OFF_HBALL   114595840ull    // f32 [512]
#define OFF_BEG     114597888ull    // int [128]
#define OFF_TN      114598400ull    // int [128]
#define OFF_SCORES  114598912ull    // f32 [128][3]
#define OFF_FK      114600448ull    // f32 [4][16384][4]
#define OFF_AL      115649024ull    // f32 [4][128][128][4]
#define OFF_SP      116697600ull    // f32 [4][128][128]
#define OFF_SPSUM   116959744ull    // f32 [4][128]
#define OFF_SV      116961792ull    // f32 [128][2048]

__device__ __forceinline__ float sig_f(float x) { return 1.f / (1.f + __expf(-x)); }
__device__ __forceinline__ float tanh_f(float x) { float e = __expf(2.f * x); return 1.f - 2.f / (e + 1.f); }

// ---------------- zero ctx + ctxb ----------------
__global__ __launch_bounds__(256) void k_zero(float4* p) {
    size_t n4 = (size_t)(33554432 + 16777216) / 16;
    for (size_t i = blockIdx.x * 256ull + threadIdx.x; i < n4; i += (size_t)gridDim.x * 256ull)
        p[i] = make_float4(0.f, 0.f, 0.f, 0.f);
}

// ---------------- prep: x_bf16 [16384][352] ----------------
__global__ __launch_bounds__(256) void k_prep_x(const float* __restrict__ sents,
        const float* __restrict__ mask_table, const int* __restrict__ masks,
        __hip_bfloat16* __restrict__ xbf) {
    int idx = blockIdx.x * 256 + threadIdx.x;
    if (idx >= MTOT * KP) return;
    int m = idx / KP, k = idx % KP;
    float v = 0.f;
    if (k < DD) v = sents[(size_t)m * DD + k];
    else if (k < GINDIM) v = mask_table[masks[m] * MDIM + (k - DD)];
    xbf[idx] = __float2bfloat16(v);
}

// ---------------- prep: WihB bf16 [1536][352] + biasAll ----------------
__global__ __launch_bounds__(256) void k_prep_wihB(const float* __restrict__ Wf,
        const float* __restrict__ Wb, const float* __restrict__ bf_,
        const float* __restrict__ bb_, __hip_bfloat16* __restrict__ wihB,
        float* __restrict__ biasAll) {
    int idx = blockIdx.x * 256 + threadIdx.x;
    if (idx < N2 * KP) {
        int n = idx / KP, k = idx % KP;
        int dir = n >= G3; int g = n - dir * G3;
        const float* W = dir ? Wb : Wf;
        float v = (k < GINDIM) ? W[(size_t)g * GINDIM + k] : 0.f;
        wihB[idx] = __float2bfloat16(v);
    }
    if (idx < N2) biasAll[idx] = (idx < G3) ? bf_[idx] : bb_[idx - G3];
}

// ---------------- prep: hWB bf16 [512][512] + hbAll ----------------
__global__ __launch_bounds__(256) void k_prep_hwB(const float* __restrict__ hW,
        const float* __restrict__ hb, __hip_bfloat16* __restrict__ hwB, float* __restrict__ hbAll) {
    int idx = blockIdx.x * 256 + threadIdx.x;
    if (idx < HH * HH) hwB[idx] = __float2bfloat16(hW[idx]);
    if (idx < HH) hbAll[idx] = hb[idx];
}

// ---------------- prep: WhhB bf16 [2][768][256] ----------------
__global__ __launch_bounds__(256) void k_prep_whhB(const float* __restrict__ Wf,
        const float* __restrict__ Wb, __hip_bfloat16* __restrict__ whhB) {
    int idx = blockIdx.x * 256 + threadIdx.x;
    if (idx >= 2 * G3 * HDIM) return;
    int dir = idx / (G3 * HDIM);
    const float* W = dir ? Wb : Wf;
    whhB[idx] = __float2bfloat16(W[idx - dir * G3 * HDIM]);
}

__global__ __launch_bounds__(128) void k_prep_bt(const int* __restrict__ masks,
        int* __restrict__ beg, int* __restrict__ tn) {
    int b = threadIdx.x;
    int best = masks[b * LL]; int idx = 0; int s = 0;
    for (int j = 0; j < LL; ++j) {
        int v = masks[b * LL + j]; s += v;
        if (v > best) { best = v; idx = j; }
    }
    beg[b] = idx; tn[b] = s;
}

// ---------------- MFMA GEMM 1: gi = x @ Wih^T + bias ----------------
__global__ __launch_bounds__(256) void k_mfma_gi(const short* __restrict__ xbf,
        const short* __restrict__ wihB, const float* __restrict__ biasAll,
        __hip_bfloat16* __restrict__ gi) {
    __shared__ short As[64][40];
    __shared__ short Bs[64][40];
    const int tid = threadIdx.x;
    const int m0 = blockIdx.y * 64, n0 = blockIdx.x * 64;
    const int w = tid >> 6, lane = tid & 63;
    const int srow = tid >> 2, skc = (tid & 3) * 8;
    const int frow = lane & 15, fkc = (lane >> 4) * 8;
    const int rb = (w >> 1) * 32, cb = (w & 1) * 32;
    f32x4 zero = {0.f, 0.f, 0.f, 0.f};
    f32x4 acc[2][2] = {zero, zero, zero, zero};
    for (int k0 = 0; k0 < KP; k0 += 32) {
        *(short8*)&As[srow][skc] = *(const short8*)&xbf[(size_t)(m0 + srow) * KP + k0 + skc];
        *(short8*)&Bs[srow][skc] = *(const short8*)&wihB[(size_t)(n0 + srow) * KP + k0 + skc];
        __syncthreads();
        short8 a[2], b[2];
        #pragma unroll
        for (int i = 0; i < 2; ++i) a[i] = *(const short8*)&As[rb + i * 16 + frow][fkc];
        #pragma unroll
        for (int j = 0; j < 2; ++j) b[j] = *(const short8*)&Bs[cb + j * 16 + frow][fkc];
        #pragma unroll
        for (int i = 0; i < 2; ++i)
            #pragma unroll
            for (int j = 0; j < 2; ++j)
                acc[i][j] = __builtin_amdgcn_mfma_f32_16x16x32_bf16(a[i], b[j], acc[i][j], 0, 0, 0);
        __syncthreads();
    }
    #pragma unroll
    for (int i = 0; i < 2; ++i) {
        #pragma unroll
        for (int j = 0; j < 2; ++j) {
            int col = n0 + cb + j * 16 + frow;
            int dir = col >= G3; int g = col - dir * G3;
            float bias = biasAll[col];
            #pragma unroll
            for (int r = 0; r < 4; ++r) {
                int m = m0 + rb + i * 16 + (lane >> 4) * 4 + r;
                gi[((size_t)dir * MTOT + m) * G3 + g] = __float2bfloat16(acc[i][j][r] + bias);
            }
        }
    }
}

// ---------------- MFMA GEMM 2: ck = ctxb @ hW^T + hb ----------------
__global__ __launch_bounds__(256) void k_mfma_ck(const short* __restrict__ ctxb,
        const short* __restrict__ hwB, const float* __restrict__ hbAll,
        float* __restrict__ ck) {
    __shared__ short As[64][40];
    __shared__ short Bs[64][40];
    const int tid = threadIdx.x;
    const int m0 = blockIdx.y * 64, n0 = blockIdx.x * 64;
    const int w = tid >> 6, lane = tid & 63;
    const int srow = tid >> 2, skc = (tid & 3) * 8;
    const int frow = lane & 15, fkc = (lane >> 4) * 8;
    const int rb = (w >> 1) * 32, cb = (w & 1) * 32;
    f32x4 zero = {0.f, 0.f, 0.f, 0.f};
    f32x4 acc[2][2] = {zero, zero, zero, zero};
    for (int k0 = 0; k0 < HH; k0 += 32) {
        *(short8*)&As[srow][skc] = *(const short8*)&ctxb[(size_t)(m0 + srow) * HH + k0 + skc];
        *(short8*)&Bs[srow][skc] = *(const short8*)&hwB[(size_t)(n0 + srow) * HH + k0 + skc];
        __syncthreads();
        short8 a[2], b[2];
        #pragma unroll
        for (int i = 0; i < 2; ++i) a[i] = *(const short8*)&As[rb + i * 16 + frow][fkc];
        #pragma unroll
        for (int j = 0; j < 2; ++j) b[j] = *(const short8*)&Bs[cb + j * 16 + frow][fkc];
        #pragma unroll
        for (int i = 0; i < 2; ++i)
            #pragma unroll
            for (int j = 0; j < 2; ++j)
                acc[i][j] = __builtin_amdgcn_mfma_f32_16x16x32_bf16(a[i], b[j], acc[i][j], 0, 0, 0);
        __syncthreads();
    }
    #pragma unroll
    for (int i = 0; i < 2; ++i) {
        #pragma unroll
        for (int j = 0; j < 2; ++j) {
            int col = n0 + cb + j * 16 + frow;
            float bias = hbAll[col];
            #pragma unroll
            for (int r = 0; r < 4; ++r) {
                int m = m0 + rb + i * 16 + (lane >> 4) * 4 + r;
                ck[(size_t)m * HH + col] = acc[i][j][r] + bias;
            }
        }
    }
}

// ---------------- pos weight ----------------
__device__ __forceinline__ float poswt(int j, int beg, int tn, int len, float lf, int mv) {
    float w = (j < beg) ? (1.f - (float)(beg - j) / lf) : 0.f;
    if (mv == 1) w = 1.f;
    if (j > beg + tn) w = 1.f - (float)(j - beg) / lf;
    if (j > len) w = 0.f;
    return w;
}

// ---------------- GRU recurrence via MFMA: 16 blocks (2 dir x 8 groups of 16 batches) ----------------
__global__ __launch_bounds__(512, 2) void k_gru_mfma(
        const __hip_bfloat16* __restrict__ gi, const short* __restrict__ whhB,
        const float* __restrict__ gbhhf, const float* __restrict__ gbhhb,
        const int* __restrict__ lens, const int* __restrict__ masks,
        const int* __restrict__ beg_, const int* __restrict__ tn_,
        float* __restrict__ ctx, __hip_bfloat16* __restrict__ ctxb) {
    __shared__ short hA[16][264];     // bf16 hidden, padded (2-way LDS conflict = free)
    __shared__ float gates[16][772];  // padded gate pre-activations
    __shared__ float s_w[16][128];    // pos weights
    __shared__ int s_len[16];
    __shared__ int s_maxlen;

    const int tid = threadIdx.x;
    const int w = tid >> 6, lane = tid & 63;
    const int dir = blockIdx.x >> 3, grp = blockIdx.x & 7;
    const int b0 = grp * 16;
    const int frow = lane & 15, fkc = (lane >> 4) * 8;
    const int colg = w * 96;

    if (tid < 16) s_len[tid] = lens[b0 + tid];
    for (int e = tid; e < 16 * 264; e += 512) ((short*)hA)[e] = 0;
    __syncthreads();
    if (tid == 0) {
        int m = 0;
        #pragma unroll
        for (int q = 0; q < 16; ++q) m = max(m, s_len[q]);
        s_maxlen = m;
    }
    for (int e = tid; e < 16 * 128; e += 512) {
        int bl = e >> 7, j = e & 127;
        int b = b0 + bl;
        int len = s_len[bl];
        s_w[bl][j] = poswt(j, beg_[b], tn_[b], len, (float)len, masks[b * LL + j]);
    }

    // preload all B fragments (wave w owns gate cols [w*96, w*96+96))
    short8 bu[48];
    #pragma unroll
    for (int ct = 0; ct < 6; ++ct)
        #pragma unroll
        for (int kk = 0; kk < 8; ++kk)
            bu[ct * 8 + kk] = *(const short8*)&whhB[((size_t)dir * G3 + colg + ct * 16 + frow) * HDIM + kk * 32 + fkc];

    const int i_idx = tid & 255;
    const int bbase = (tid >> 8) * 8;
    const float* bhh = dir ? gbhhb : gbhhf;
    const float bhr = bhh[i_idx], bhz = bhh[HDIM + i_idx], bhn = bhh[2 * HDIM + i_idx];
    const __hip_bfloat16* giD = gi + (size_t)dir * MTOT * G3;
    float hv[8];
    #pragma unroll
    for (int q = 0; q < 8; ++q) hv[q] = 0.f;
    __syncthreads();

    const int maxlen = s_maxlen;
    const f32x4 zero = {0.f, 0.f, 0.f, 0.f};
    for (int l = 0; l < maxlen; ++l) {
        f32x4 acc[6];
        #pragma unroll
        for (int ct = 0; ct < 6; ++ct) acc[ct] = zero;
        #pragma unroll
        for (int kk = 0; kk < 8; ++kk) {
            short8 a = *(const short8*)&hA[frow][kk * 32 + fkc];
            #pragma unroll
            for (int ct = 0; ct < 6; ++ct)
                acc[ct] = __builtin_amdgcn_mfma_f32_16x16x32_bf16(a, bu[ct * 8 + kk], acc[ct], 0, 0, 0);
        }
        #pragma unroll
        for (int ct = 0; ct < 6; ++ct) {
            int col = colg + ct * 16 + frow;
            #pragma unroll
            for (int r = 0; r < 4; ++r)
                gates[(lane >> 4) * 4 + r][col] = acc[ct][r];
        }
        __syncthreads();
        #pragma unroll
        for (int q = 0; q < 8; ++q) {
            int bl = bbase + q;
            int len = s_len[bl];
            bool valid = l < len;
            int pos = dir ? (len - 1 - l) : l;
            int posc = valid ? pos : 0;
            size_t grow = ((size_t)(b0 + bl) * LL + posc) * G3;
            float gvr = __bfloat162float(giD[grow + i_idx]);
            float gvz = __bfloat162float(giD[grow + HDIM + i_idx]);
            float gvn = __bfloat162float(giD[grow + 2 * HDIM + i_idx]);
            float rr = sig_f(gvr + gates[bl][i_idx] + bhr);
            float zz = sig_f(gvz + gates[bl][HDIM + i_idx] + bhz);
            float nn = tanh_f(gvn + rr * (gates[bl][2 * HDIM + i_idx] + bhn));
            float h = (1.f - zz) * nn + zz * hv[q];
            if (valid) {
                hv[q] = h;
                __hip_bfloat16 hb16 = __float2bfloat16(h);
                hA[bl][i_idx] = *reinterpret_cast<short*>(&hb16);
                float hw = h * s_w[bl][posc];
                size_t co = ((size_t)(b0 + bl) * LL + posc) * HH + dir * HDIM + i_idx;
                ctx[co] = hw;
                ctxb[co] = __float2bfloat16(hw);
            }
        }
        __syncthreads();
    }
}

// ---------------- fk = ck_k @ tW_k^T + tb ----------------
__global__ __launch_bounds__(256) void k_fk(const float* __restrict__ ck,
        const float* __restrict__ tW, const float* __restrict__ tb,
        float* __restrict__ fk) {
    int gid = blockIdx.x * 256 + threadIdx.x;  // MTOT*16
    int m = gid >> 4;
    int kt = gid & 15;
    int k = kt >> 2, t = kt & 3;
    const float* c = ck + (size_t)m * HH + k * RR;
    const float* w = tW + (size_t)(k * TT + t) * RR;
    float acc = tb[k * TT + t];
    #pragma unroll 4
    for (int r = 0; r < RR; ++r) acc += c[r] * w[r];
    fk[((size_t)k * MTOT + m) * TT + t] = acc;
}

// ---------------- CRF forward/backward marginals (4 lanes per (k,b)) ----------------
__global__ __launch_bounds__(64) void k_crf(const float* __restrict__ fk,
        const float* __restrict__ trans, const int* __restrict__ lens,
        float* __restrict__ alphas, float* __restrict__ sp, float* __restrict__ spsum) {
    const int tid = blockIdx.x * 64 + threadIdx.x;   // 2048 total
    const int pid = tid >> 2;                        // 512 pairs
    const int t = tid & 3;
    const int k = pid >> 7, b = pid & 127;
    const int len = lens[b];
    const float* f = fk + ((size_t)k * MTOT + (size_t)b * LL) * TT;
    const float* tr = trans + k * 16;
    const float trC0 = tr[0 * 4 + t], trC1 = tr[1 * 4 + t], trC2 = tr[2 * 4 + t], trC3 = tr[3 * 4 + t];
    const float trR0 = tr[t * 4 + 0], trR1 = tr[t * 4 + 1], trR2 = tr[t * 4 + 2], trR3 = tr[t * 4 + 3];
    float* al = alphas + ((size_t)k * BB + b) * LL * TT;
    const int base = threadIdx.x & ~3;
    float alpha = f[t];
    al[t] = alpha;
    for (int l = 1; l < LL; ++l) {
        float a0 = __shfl(alpha, base + 0);
        float a1 = __shfl(alpha, base + 1);
        float a2 = __shfl(alpha, base + 2);
        float a3 = __shfl(alpha, base + 3);
        float v0 = a0 + trC0, v1 = a1 + trC1, v2 = a2 + trC2, v3 = a3 + trC3;
        float mx = fmaxf(fmaxf(v0, v1), fmaxf(v2, v3));
        float sum = __expf(v0 - mx) + __expf(v1 - mx) + __expf(v2 - mx) + __expf(v3 - mx);
        float nw = mx + __logf(sum) + f[l * TT + t];
        if (l < len) alpha = nw;
        al[l * TT + t] = alpha;
    }
    float beta = 0.f;
    float ssum = 0.f;
    for (int l = LL - 1; l >= 0; --l) {
        if (l < LL - 1) {
            float fb = f[(l + 1) * TT + t] + beta;
            float c0 = __shfl(fb, base + 0);
            float c1 = __shfl(fb, base + 1);
            float c2 = __shfl(fb, base + 2);
            float c3 = __shfl(fb, base + 3);
            float w0 = trR0 + c0, w1 = trR1 + c1, w2 = trR2 + c2, w3 = trR3 + c3;
            float mx = fmaxf(fmaxf(w0, w1), fmaxf(w2, w3));
            float nb = mx + __logf(__expf(w0 - mx) + __expf(w1 - mx) + __expf(w2 - mx) + __expf(w3 - mx));
            if (l + 1 < len) beta = nb;
        }
        float v = al[l * TT + t] + beta;
        float mx = fmaxf(v, __shfl_xor(v, 1));
        mx = fmaxf(mx, __shfl_xor(mx, 2));
        float p = __expf(v - mx);
        float s = p;
        s += __shfl_xor(s, 1);
        s += __shfl_xor(s, 2);
        float m1 = __shfl(p, base + 1) / s;
        float spv = (l < len) ? m1 : 0.f;
        if (t == 0) sp[((size_t)k * BB + b) * LL + l] = spv;
        ssum += spv;
    }
    if (t == 0) spsum[k * BB + b] = ssum;
}

// ---------------- pooling: sv[b, k*512+h] ----------------
__global__ __launch_bounds__(256) void k_pool(const float* __restrict__ ctx,
        const float* __restrict__ sp, const float* __restrict__ spsum,
        float* __restrict__ sv) {
    __shared__ float s_sp[NKB][LL];
    __shared__ float s_inv[NKB];
    const int b = blockIdx.x;
    const int tid = threadIdx.x;
    for (int i = tid; i < NKB * LL; i += 256) {
        int k = i >> 7, l = i & 127;
        s_sp[k][l] = sp[((size_t)k * BB + b) * LL + l];
    }
    if (tid < NKB) s_inv[tid] = 1.f / spsum[tid * BB + b];
    __syncthreads();
    #pragma unroll
    for (int i = 0; i < 8; ++i) {
        int n = tid + i * 256;
        int k = n >> 9, h = n & 511;
        float acc = 0.f;
        for (int l = 0; l < LL; ++l)
            acc += s_sp[k][l] * ctx[((size_t)b * LL + l) * HH + h];
        sv[(size_t)b * 2048 + n] = acc * s_inv[k];
    }
}

// ---------------- scores[b][3] = relu(sv[b]) @ lW^T + lb ----------------
__global__ __launch_bounds__(256) void k_scores(const float* __restrict__ sv,
        const float* __restrict__ lW, const float* __restrict__ lb,
        float* __restrict__ scores) {
    __shared__ float red[3][4];
    const int b = blockIdx.x;
    const int tid = threadIdx.x;
    const float* svb = sv + (size_t)b * 2048;
    float a0 = 0.f, a1 = 0.f, a2 = 0.f;
    for (int i = tid; i < 2048; i += 256) {
        float v = fmaxf(svb[i], 0.f);
        a0 += v * lW[i];
        a1 += v * lW[2048 + i];
        a2 += v * lW[4096 + i];
    }
    #pragma unroll
    for (int off = 32; off > 0; off >>= 1) {
        a0 += __shfl_down(a0, off);
        a1 += __shfl_down(a1, off);
        a2 += __shfl_down(a2, off);
    }
    const int wid = tid >> 6, lane = tid & 63;
    if (lane == 0) { red[0][wid] = a0; red[1][wid] = a1; red[2][wid] = a2; }
    __syncthreads();
    if (tid < 3) {
        scores[b * 3 + tid] = red[tid][0] + red[tid][1] + red[tid][2] + red[tid][3] + lb[tid];
    }
}

// ---------------- final: log-softmax + mean NLL (float32 out) ----------------
__global__ __launch_bounds__(128) void k_final2(const float* __restrict__ scores,
        const int* __restrict__ labels, float* __restrict__ out) {
    __shared__ float red[128];
    const int b = threadIdx.x;
    float s0 = scores[b * 3 + 0], s1 = scores[b * 3 + 1], s2 = scores[b * 3 + 2];
    float mx = fmaxf(s0, fmaxf(s1, s2));
    float lse = mx + logf(expf(s0 - mx) + expf(s1 - mx) + expf(s2 - mx));
    int lab = labels[b];
    float sc = lab == 0 ? s0 : (lab == 1 ? s1 : s2);
    red[b] = lse - sc;
    __syncthreads();
    for (int st = 64; st > 0; st >>= 1) {
        if (b < st) red[b] += red[b + st];
        __syncthreads();
    }
    if (b == 0) out[0] = red[0] * (1.f / 128.f);
}

extern "C" void kernel_launch(void* const* d_in, const int* in_sizes, int n_in,
                              void* d_out, int out_size, void* d_ws, size_t ws_size,
                              hipStream_t stream) {
    const float* sents      = (const float*)d_in[0];
    const float* mask_table = (const float*)d_in[1];
    const float* gWihf      = (const float*)d_in[2];
    const float* gWhhf      = (const float*)d_in[3];
    const float* gbihf      = (const float*)d_in[4];
    const float* gbhhf      = (const float*)d_in[5];
    const float* gWihb      = (const float*)d_in[6];
    const float* gWhhb      = (const float*)d_in[7];
    const float* gbihb      = (const float*)d_in[8];
    const float* gbhhb      = (const float*)d_in[9];
    const float* hW         = (const float*)d_in[10];
    const float* hb         = (const float*)d_in[11];
    const float* tW         = (const float*)d_in[12];
    const float* tb         = (const float*)d_in[13];
    const float* trans      = (const float*)d_in[14];
    const float* lW         = (const float*)d_in[15];
    const float* lb         = (const float*)d_in[16];
    const int*   masks      = (const int*)d_in[17];
    const int*   lens       = (const int*)d_in[18];
    const int*   labels     = (const int*)d_in[19];

    char* wsb = (char*)d_ws;
    __hip_bfloat16* gi    = (__hip_bfloat16*)(wsb + OFF_GI);
    float* ck             = (float*)(wsb + OFF_CK);     // reuses gi region
    float* ctx            = (float*)(wsb + OFF_CTX);
    __hip_bfloat16* ctxb  = (__hip_bfloat16*)(wsb + OFF_CTXB);
    __hip_bfloat16* xbf   = (__hip_bfloat16*)(wsb + OFF_XBF);
    __hip_bfloat16* wihB  = (__hip_bfloat16*)(wsb + OFF_WIHB);
    __hip_bfloat16* hwB   = (__hip_bfloat16*)(wsb + OFF_HWB);
    __hip_bfloat16* whhB  = (__hip_bfloat16*)(wsb + OFF_WHHB);
    float* biasAll        = (float*)(wsb + OFF_BIAS);
    float* hbAll          = (float*)(wsb + OFF_HBALL);
    int* beg              = (int*)(wsb + OFF_BEG);
    int* tn               = (int*)(wsb + OFF_TN);
    float* scores         = (float*)(wsb + OFF_SCORES);
    float* fk             = (float*)(wsb + OFF_FK);
    float* alphas         = (float*)(wsb + OFF_AL);
    float* sp             = (float*)(wsb + OFF_SP);
    float* spsum          = (float*)(wsb + OFF_SPSUM);
    float* sv             = (float*)(wsb + OFF_SV);

    hipLaunchKernelGGL(k_zero, dim3(2048), dim3(256), 0, stream, (float4*)(wsb + OFF_CTX));
    hipLaunchKernelGGL(k_prep_x, dim3((MTOT * KP + 255) / 256), dim3(256), 0, stream,
                       sents, mask_table, masks, xbf);
    hipLaunchKernelGGL(k_prep_wihB, dim3((N2 * KP + 255) / 256), dim3(256), 0, stream,
                       gWihf, gWihb, gbihf, gbihb, wihB, biasAll);
    hipLaunchKernelGGL(k_prep_hwB, dim3((HH * HH + 255) / 256), dim3(256), 0, stream,
                       hW, hb, hwB, hbAll);
    hipLaunchKernelGGL(k_prep_whhB, dim3((2 * G3 * HDIM + 255) / 256), dim3(256), 0, stream,
                       gWhhf, gWhhb, whhB);
    hipLaunchKernelGGL(k_prep_bt, dim3(1), dim3(128), 0, stream, masks, beg, tn);

    hipLaunchKernelGGL(k_mfma_gi, dim3(N2 / 64, MTOT / 64), dim3(256), 0, stream,
                       (const short*)xbf, (const short*)wihB, biasAll, gi);
    hipLaunchKernelGGL(k_gru_mfma, dim3(16), dim3(512), 0, stream,
                       gi, (const short*)whhB, gbhhf, gbhhb, lens, masks, beg, tn, ctx, ctxb);
    hipLaunchKernelGGL(k_mfma_ck, dim3(HH / 64, MTOT / 64), dim3(256), 0, stream,
                       (const short*)ctxb, (const short*)hwB, hbAll, ck);
    hipLaunchKernelGGL(k_fk, dim3(MTOT * 16 / 256), dim3(256), 0, stream, ck, tW, tb, fk);
    hipLaunchKernelGGL(k_crf, dim3(32), dim3(64), 0, stream, fk, trans, lens, alphas, sp, spsum);
    hipLaunchKernelGGL(k_pool, dim3(BB), dim3(256), 0, stream, ctx, sp, spsum, sv);
    hipLaunchKernelGGL(k_scores, dim3(BB), dim3(256), 0, stream, sv, lW, lb, scores);
    hipLaunchKernelGGL(k_final2, dim3(1), dim3(128), 0, stream, scores, labels, (float*)d_out);
}

// Round 5
// 970.178 us; speedup vs baseline: 2.2748x; 1.1290x over previous
//
#include <hip/hip_runtime.h>
#include <hip/hip_bf16.h>

#define BB 128
#define LL 128
#define DD 300
#define MDIM 50
#define GINDIM 350
#define HDIM 256     // per-direction hidden
#define G3 768       // 3*HDIM
#define HH 512       // ctx dim
#define RR 128
#define TT 4
#define NKB 4        // branches
#define MTOT (BB*LL) // 16384
#define N2 1536      // both dirs stacked gates
#define KP 352       // padded GRU-input K

typedef __attribute__((ext_vector_type(8))) short short8;
typedef __attribute__((ext_vector_type(4))) float f32x4;

// ---------------- ws layout (bytes) ----------------
#define OFF_GI      0ull            // bf16 [2][16384][768] = 50,331,648
#define OFF_CTXB    50331648ull     // bf16 [16384][512] = 16,777,216
#define OFF_XBF     67108864ull     // bf16 [16384][352] = 11,534,336
#define OFF_WIHB    78643200ull     // bf16 [1536][352]  = 1,081,344
#define OFF_WHHB    79724544ull     // bf16 [2][768][256]= 786,432
#define OFF_BIAS    80510976ull     // f32 [1536]
#define OFF_W2      80517120ull     // f32 [16][512] = 32,768
#define OFF_B2      80549888ull     // f32 [16]
#define OFF_BEG     80550144ull     // int [128]
#define OFF_TN      80550656ull     // int [128]
#define OFF_SCORES  80551168ull     // f32 [128][3]
#define OFF_FK      80553216ull     // f32 [4][16384][4] = 1,048,576
#define OFF_AL      81601792ull     // f32 [4][128][128][4] = 1,048,576
#define OFF_SP      82650368ull     // f32 [4][128][128] = 262,144
#define OFF_SPSUM   82912512ull     // f32 [4][128]
#define OFF_SV      82914560ull     // f32 [128][2048] = 1,048,576

__device__ __forceinline__ float sig_f(float x) { return 1.f / (1.f + __expf(-x)); }
__device__ __forceinline__ float tanh_f(float x) { float e = __expf(2.f * x); return 1.f - 2.f / (e + 1.f); }
__device__ __forceinline__ float b2f(unsigned short u) { return __uint_as_float(((unsigned)u) << 16); }

// ---------------- zero ctxb ----------------
__global__ __launch_bounds__(256) void k_zero(float4* p) {
    size_t n4 = 16777216ull / 16;
    for (size_t i = blockIdx.x * 256ull + threadIdx.x; i < n4; i += (size_t)gridDim.x * 256ull)
        p[i] = make_float4(0.f, 0.f, 0.f, 0.f);
}

// ---------------- prep: x_bf16 [16384][352] ----------------
__global__ __launch_bounds__(256) void k_prep_x(const float* __restrict__ sents,
        const float* __restrict__ mask_table, const int* __restrict__ masks,
        __hip_bfloat16* __restrict__ xbf) {
    int idx = blockIdx.x * 256 + threadIdx.x;
    if (idx >= MTOT * KP) return;
    int m = idx / KP, k = idx % KP;
    float v = 0.f;
    if (k < DD) v = sents[(size_t)m * DD + k];
    else if (k < GINDIM) v = mask_table[masks[m] * MDIM + (k - DD)];
    xbf[idx] = __float2bfloat16(v);
}

// ---------------- prep: WihB bf16 [1536][352] + biasAll ----------------
__global__ __launch_bounds__(256) void k_prep_wihB(const float* __restrict__ Wf,
        const float* __restrict__ Wb, const float* __restrict__ bf_,
        const float* __restrict__ bb_, __hip_bfloat16* __restrict__ wihB,
        float* __restrict__ biasAll) {
    int idx = blockIdx.x * 256 + threadIdx.x;
    if (idx < N2 * KP) {
        int n = idx / KP, k = idx % KP;
        int dir = n >= G3; int g = n - dir * G3;
        const float* W = dir ? Wb : Wf;
        float v = (k < GINDIM) ? W[(size_t)g * GINDIM + k] : 0.f;
        wihB[idx] = __float2bfloat16(v);
    }
    if (idx < N2) biasAll[idx] = (idx < G3) ? bf_[idx] : bb_[idx - G3];
}

// ---------------- prep: WhhB bf16 [2][768][256] ----------------
__global__ __launch_bounds__(256) void k_prep_whhB(const float* __restrict__ Wf,
        const float* __restrict__ Wb, __hip_bfloat16* __restrict__ whhB) {
    int idx = blockIdx.x * 256 + threadIdx.x;
    if (idx >= 2 * G3 * HDIM) return;
    int dir = idx / (G3 * HDIM);
    const float* W = dir ? Wb : Wf;
    whhB[idx] = __float2bfloat16(W[idx - dir * G3 * HDIM]);
}

// ---------------- prep: W2[kt][512] = tW_k[t] @ hW_k ; b2 ----------------
__global__ __launch_bounds__(256) void k_prep_w2(const float* __restrict__ hW,
        const float* __restrict__ hb, const float* __restrict__ tW,
        const float* __restrict__ tb, float* __restrict__ W2, float* __restrict__ b2) {
    int idx = blockIdx.x * 256 + threadIdx.x;   // 16*512
    if (idx < 16 * HH) {
        int kt = idx >> 9, h = idx & 511;
        int k = kt >> 2, t = kt & 3;
        const float* tw = tW + (size_t)(k * TT + t) * RR;
        const float* hw = hW + (size_t)k * RR * HH + h;
        float acc = 0.f;
        #pragma unroll 4
        for (int r = 0; r < RR; ++r) acc += tw[r] * hw[(size_t)r * HH];
        W2[idx] = acc;
    }
    if (idx < 16) {
        int k = idx >> 2, t = idx & 3;
        const float* tw = tW + (size_t)(k * TT + t) * RR;
        const float* hbk = hb + k * RR;
        float acc = tb[k * TT + t];
        for (int r = 0; r < RR; ++r) acc += tw[r] * hbk[r];
        b2[idx] = acc;
    }
}

__global__ __launch_bounds__(128) void k_prep_bt(const int* __restrict__ masks,
        int* __restrict__ beg, int* __restrict__ tn) {
    int b = threadIdx.x;
    int best = masks[b * LL]; int idx = 0; int s = 0;
    for (int j = 0; j < LL; ++j) {
        int v = masks[b * LL + j]; s += v;
        if (v > best) { best = v; idx = j; }
    }
    beg[b] = idx; tn[b] = s;
}

// ---------------- MFMA GEMM 1: gi = x @ Wih^T + bias ----------------
__global__ __launch_bounds__(256) void k_mfma_gi(const short* __restrict__ xbf,
        const short* __restrict__ wihB, const float* __restrict__ biasAll,
        __hip_bfloat16* __restrict__ gi) {
    __shared__ short As[64][40];
    __shared__ short Bs[64][40];
    const int tid = threadIdx.x;
    const int m0 = blockIdx.y * 64, n0 = blockIdx.x * 64;
    const int w = tid >> 6, lane = tid & 63;
    const int srow = tid >> 2, skc = (tid & 3) * 8;
    const int frow = lane & 15, fkc = (lane >> 4) * 8;
    const int rb = (w >> 1) * 32, cb = (w & 1) * 32;
    f32x4 zero = {0.f, 0.f, 0.f, 0.f};
    f32x4 acc[2][2] = {zero, zero, zero, zero};
    for (int k0 = 0; k0 < KP; k0 += 32) {
        *(short8*)&As[srow][skc] = *(const short8*)&xbf[(size_t)(m0 + srow) * KP + k0 + skc];
        *(short8*)&Bs[srow][skc] = *(const short8*)&wihB[(size_t)(n0 + srow) * KP + k0 + skc];
        __syncthreads();
        short8 a[2], b[2];
        #pragma unroll
        for (int i = 0; i < 2; ++i) a[i] = *(const short8*)&As[rb + i * 16 + frow][fkc];
        #pragma unroll
        for (int j = 0; j < 2; ++j) b[j] = *(const short8*)&Bs[cb + j * 16 + frow][fkc];
        #pragma unroll
        for (int i = 0; i < 2; ++i)
            #pragma unroll
            for (int j = 0; j < 2; ++j)
                acc[i][j] = __builtin_amdgcn_mfma_f32_16x16x32_bf16(a[i], b[j], acc[i][j], 0, 0, 0);
        __syncthreads();
    }
    #pragma unroll
    for (int i = 0; i < 2; ++i) {
        #pragma unroll
        for (int j = 0; j < 2; ++j) {
            int col = n0 + cb + j * 16 + frow;
            int dir = col >= G3; int g = col - dir * G3;
            float bias = biasAll[col];
            #pragma unroll
            for (int r = 0; r < 4; ++r) {
                int m = m0 + rb + i * 16 + (lane >> 4) * 4 + r;
                gi[((size_t)dir * MTOT + m) * G3 + g] = __float2bfloat16(acc[i][j][r] + bias);
            }
        }
    }
}

// ---------------- pos weight ----------------
__device__ __forceinline__ float poswt(int j, int beg, int tn, int len, float lf, int mv) {
    float w = (j < beg) ? (1.f - (float)(beg - j) / lf) : 0.f;
    if (mv == 1) w = 1.f;
    if (j > beg + tn) w = 1.f - (float)(j - beg) / lf;
    if (j > len) w = 0.f;
    return w;
}

// ---------------- GRU recurrence via MFMA: 16 blocks (2 dir x 8 groups of 16 batches) ----------------
__global__ __launch_bounds__(512, 1) void k_gru_mfma(
        const __hip_bfloat16* __restrict__ gi, const short* __restrict__ whhB,
        const float* __restrict__ gbhhf, const float* __restrict__ gbhhb,
        const int* __restrict__ lens, const int* __restrict__ masks,
        const int* __restrict__ beg_, const int* __restrict__ tn_,
        __hip_bfloat16* __restrict__ ctxb) {
    __shared__ short hA[16][264];     // bf16 hidden, padded
    __shared__ float gates[16][772];  // padded gate pre-activations
    __shared__ float s_w[16][128];    // pos weights
    __shared__ int s_len[16];
    __shared__ int s_maxlen;

    const int tid = threadIdx.x;
    const int w = tid >> 6, lane = tid & 63;
    const int dir = blockIdx.x >> 3, grp = blockIdx.x & 7;
    const int b0 = grp * 16;
    const int frow = lane & 15, fkc = (lane >> 4) * 8;
    const int colg = w * 96;

    if (tid < 16) s_len[tid] = lens[b0 + tid];
    for (int e = tid; e < 16 * 264; e += 512) ((short*)hA)[e] = 0;
    __syncthreads();
    if (tid == 0) {
        int m = 0;
        #pragma unroll
        for (int q = 0; q < 16; ++q) m = max(m, s_len[q]);
        s_maxlen = m;
    }
    for (int e = tid; e < 16 * 128; e += 512) {
        int bl = e >> 7, j = e & 127;
        int b = b0 + bl;
        int len = s_len[bl];
        s_w[bl][j] = poswt(j, beg_[b], tn_[b], len, (float)len, masks[b * LL + j]);
    }

    // preload all B fragments (wave w owns gate cols [w*96, w*96+96))
    short8 bu[48];
    #pragma unroll
    for (int ct = 0; ct < 6; ++ct)
        #pragma unroll
        for (int kk = 0; kk < 8; ++kk)
            bu[ct * 8 + kk] = *(const short8*)&whhB[((size_t)dir * G3 + colg + ct * 16 + frow) * HDIM + kk * 32 + fkc];

    const int i_idx = tid & 255;
    const int bbase = (tid >> 8) * 8;
    const float* bhh = dir ? gbhhb : gbhhf;
    const float bhr = bhh[i_idx], bhz = bhh[HDIM + i_idx], bhn = bhh[2 * HDIM + i_idx];
    const unsigned short* giD = (const unsigned short*)gi + (size_t)dir * MTOT * G3;
    float hv[8];
    #pragma unroll
    for (int q = 0; q < 8; ++q) hv[q] = 0.f;
    __syncthreads();

    const int maxlen = s_maxlen;
    const f32x4 zero = {0.f, 0.f, 0.f, 0.f};
    for (int l = 0; l < maxlen; ++l) {
        // ---- prefetch gi for this step (issued before MFMA; consumed after barrier) ----
        unsigned short g0[8], g1[8], g2[8];
        #pragma unroll
        for (int q = 0; q < 8; ++q) {
            int bl = bbase + q;
            int len = s_len[bl];
            int pos = dir ? (len - 1 - l) : l;
            if (l >= len) pos = 0;
            const unsigned short* grow = giD + ((size_t)(b0 + bl) * LL + pos) * G3 + i_idx;
            g0[q] = grow[0];
            g1[q] = grow[HDIM];
            g2[q] = grow[2 * HDIM];
        }
        // ---- MFMA: gates_pre = h @ Whh^T ----
        f32x4 acc[6];
        #pragma unroll
        for (int ct = 0; ct < 6; ++ct) acc[ct] = zero;
        #pragma unroll
        for (int kk = 0; kk < 8; ++kk) {
            short8 a = *(const short8*)&hA[frow][kk * 32 + fkc];
            #pragma unroll
            for (int ct = 0; ct < 6; ++ct)
                acc[ct] = __builtin_amdgcn_mfma_f32_16x16x32_bf16(a, bu[ct * 8 + kk], acc[ct], 0, 0, 0);
        }
        #pragma unroll
        for (int ct = 0; ct < 6; ++ct) {
            int col = colg + ct * 16 + frow;
            #pragma unroll
            for (int r = 0; r < 4; ++r)
                gates[(lane >> 4) * 4 + r][col] = acc[ct][r];
        }
        __syncthreads();
        // ---- nonlinearity (gi already in registers) ----
        #pragma unroll
        for (int q = 0; q < 8; ++q) {
            int bl = bbase + q;
            int len = s_len[bl];
            bool valid = l < len;
            int pos = dir ? (len - 1 - l) : l;
            if (!valid) pos = 0;
            float rr = sig_f(b2f(g0[q]) + gates[bl][i_idx] + bhr);
            float zz = sig_f(b2f(g1[q]) + gates[bl][HDIM + i_idx] + bhz);
            float nn = tanh_f(b2f(g2[q]) + rr * (gates[bl][2 * HDIM + i_idx] + bhn));
            float h = (1.f - zz) * nn + zz * hv[q];
            if (valid) {
                hv[q] = h;
                __hip_bfloat16 hb16 = __float2bfloat16(h);
                hA[bl][i_idx] = *reinterpret_cast<short*>(&hb16);
                float hw = h * s_w[bl][pos];
                ctxb[((size_t)(b0 + bl) * LL + pos) * HH + dir * HDIM + i_idx] = __float2bfloat16(hw);
            }
        }
        __syncthreads();
    }
}

// ---------------- fused fk = ctxb @ W2^T + b2 ----------------
__global__ __launch_bounds__(256) void k_fk(const __hip_bfloat16* __restrict__ ctxb,
        const float* __restrict__ W2, const float* __restrict__ b2,
        float* __restrict__ fk) {
    int gid = blockIdx.x * 256 + threadIdx.x;  // MTOT*16
    int m = gid >> 4, kt = gid & 15;
    const short8* crow = (const short8*)((const short*)ctxb + (size_t)m * HH);
    const float* w2 = W2 + kt * HH;
    float acc = b2[kt];
    #pragma unroll 4
    for (int c = 0; c < HH / 8; ++c) {
        short8 v = crow[c];
        #pragma unroll
        for (int j = 0; j < 8; ++j)
            acc += b2f((unsigned short)v[j]) * w2[c * 8 + j];
    }
    fk[((size_t)(kt >> 2) * MTOT + m) * TT + (kt & 3)] = acc;
}

// ---------------- CRF forward/backward marginals (4 lanes per (k,b)) ----------------
__global__ __launch_bounds__(64) void k_crf(const float* __restrict__ fk,
        const float* __restrict__ trans, const int* __restrict__ lens,
        float* __restrict__ alphas, float* __restrict__ sp, float* __restrict__ spsum) {
    const int tid = blockIdx.x * 64 + threadIdx.x;   // 2048 total
    const int pid = tid >> 2;                        // 512 pairs
    const int t = tid & 3;
    const int k = pid >> 7, b = pid & 127;
    const int len = lens[b];
    const float* f = fk + ((size_t)k * MTOT + (size_t)b * LL) * TT;
    const float* tr = trans + k * 16;
    const float trC0 = tr[0 * 4 + t], trC1 = tr[1 * 4 + t], trC2 = tr[2 * 4 + t], trC3 = tr[3 * 4 + t];
    const float trR0 = tr[t * 4 + 0], trR1 = tr[t * 4 + 1], trR2 = tr[t * 4 + 2], trR3 = tr[t * 4 + 3];
    float* al = alphas + ((size_t)k * BB + b) * LL * TT;
    const int base = threadIdx.x & ~3;
    float alpha = f[t];
    al[t] = alpha;
    for (int l = 1; l < LL; ++l) {
        float a0 = __shfl(alpha, base + 0);
        float a1 = __shfl(alpha, base + 1);
        float a2 = __shfl(alpha, base + 2);
        float a3 = __shfl(alpha, base + 3);
        float v0 = a0 + trC0, v1 = a1 + trC1, v2 = a2 + trC2, v3 = a3 + trC3;
        float mx = fmaxf(fmaxf(v0, v1), fmaxf(v2, v3));
        float sum = __expf(v0 - mx) + __expf(v1 - mx) + __expf(v2 - mx) + __expf(v3 - mx);
        float nw = mx + __logf(sum) + f[l * TT + t];
        if (l < len) alpha = nw;
        al[l * TT + t] = alpha;
    }
    float beta = 0.f;
    float ssum = 0.f;
    for (int l = LL - 1; l >= 0; --l) {
        if (l < LL - 1) {
            float fb = f[(l + 1) * TT + t] + beta;
            float c0 = __shfl(fb, base + 0);
            float c1 = __shfl(fb, base + 1);
            float c2 = __shfl(fb, base + 2);
            float c3 = __shfl(fb, base + 3);
            float w0 = trR0 + c0, w1 = trR1 + c1, w2 = trR2 + c2, w3 = trR3 + c3;
            float mx = fmaxf(fmaxf(w0, w1), fmaxf(w2, w3));
            float nb = mx + __logf(__expf(w0 - mx) + __expf(w1 - mx) + __expf(w2 - mx) + __expf(w3 - mx));
            if (l + 1 < len) beta = nb;
        }
        float v = al[l * TT + t] + beta;
        float mx = fmaxf(v, __shfl_xor(v, 1));
        mx = fmaxf(mx, __shfl_xor(mx, 2));
        float p = __expf(v - mx);
        float s = p;
        s += __shfl_xor(s, 1);
        s += __shfl_xor(s, 2);
        float m1 = __shfl(p, base + 1) / s;
        float spv = (l < len) ? m1 : 0.f;
        if (t == 0) sp[((size_t)k * BB + b) * LL + l] = spv;
        ssum += spv;
    }
    if (t == 0) spsum[k * BB + b] = ssum;
}

// ---------------- pooling: sv[b, k*512+h] (bf16 ctx, vectorized) ----------------
__global__ __launch_bounds__(256) void k_pool(const __hip_bfloat16* __restrict__ ctxb,
        const float* __restrict__ sp, const float* __restrict__ spsum,
        float* __restrict__ sv) {
    __shared__ float s_sp[NKB][LL];
    __shared__ float s_inv[NKB];
    const int b = blockIdx.x;
    const int tid = threadIdx.x;
    for (int i = tid; i < NKB * LL; i += 256) {
        int k = i >> 7, l = i & 127;
        s_sp[k][l] = sp[((size_t)k * BB + b) * LL + l];
    }
    if (tid < NKB) s_inv[tid] = 1.f / spsum[tid * BB + b];
    __syncthreads();
    const int n0 = tid * 8;
    const int k = n0 >> 9, h0 = n0 & 511;
    float acc[8] = {};
    const short* cb = (const short*)ctxb;
    for (int l = 0; l < LL; ++l) {
        float spl = s_sp[k][l];
        short8 v = *(const short8*)&cb[((size_t)b * LL + l) * HH + h0];
        #pragma unroll
        for (int j = 0; j < 8; ++j)
            acc[j] += spl * b2f((unsigned short)v[j]);
    }
    float inv = s_inv[k];
    #pragma unroll
    for (int j = 0; j < 8; ++j)
        sv[(size_t)b * 2048 + n0 + j] = acc[j] * inv;
}

// ---------------- scores[b][3] = relu(sv[b]) @ lW^T + lb ----------------
__global__ __launch_bounds__(256) void k_scores(const float* __restrict__ sv,
        const float* __restrict__ lW, const float* __restrict__ lb,
        float* __restrict__ scores) {
    __shared__ float red[3][4];
    const int b = blockIdx.x;
    const int tid = threadIdx.x;
    const float* svb = sv + (size_t)b * 2048;
    float a0 = 0.f, a1 = 0.f, a2 = 0.f;
    for (int i = tid; i < 2048; i += 256) {
        float v = fmaxf(svb[i], 0.f);
        a0 += v * lW[i];
        a1 += v * lW[2048 + i];
        a2 += v * lW[4096 + i];
    }
    #pragma unroll
    for (int off = 32; off > 0; off >>= 1) {
        a0 += __shfl_down(a0, off);
        a1 += __shfl_down(a1, off);
        a2 += __shfl_down(a2, off);
    }
    const int wid = tid >> 6, lane = tid & 63;
    if (lane == 0) { red[0][wid] = a0; red[1][wid] = a1; red[2][wid] = a2; }
    __syncthreads();
    if (tid < 3) {
        scores[b * 3 + tid] = red[tid][0] + red[tid][1] + red[tid][2] + red[tid][3] + lb[tid];
    }
}

// ---------------- final: log-softmax + mean NLL (float32 out) ----------------
__global__ __launch_bounds__(128) void k_final2(const float* __restrict__ scores,
        const int* __restrict__ labels, float* __restrict__ out) {
    __shared__ float red[128];
    const int b = threadIdx.x;
    float s0 = scores[b * 3 + 0], s1 = scores[b * 3 + 1], s2 = scores[b * 3 + 2];
    float mx = fmaxf(s0, fmaxf(s1, s2));
    float lse = mx + logf(expf(s0 - mx) + expf(s1 - mx) + expf(s2 - mx));
    int lab = labels[b];
    float sc = lab == 0 ? s0 : (lab == 1 ? s1 : s2);
    red[b] = lse - sc;
    __syncthreads();
    for (int st = 64; st > 0; st >>= 1) {
        if (b < st) red[b] += red[b + st];
        __syncthreads();
    }
    if (b == 0) out[0] = red[0] * (1.f / 128.f);
}

extern "C" void kernel_launch(void* const* d_in, const int* in_sizes, int n_in,
                              void* d_out, int out_size, void* d_ws, size_t ws_size,
                              hipStream_t stream) {
    const float* sents      = (const float*)d_in[0];
    const float* mask_table = (const float*)d_in[1];
    const float* gWihf      = (const float*)d_in[2];
    const float* gWhhf      = (const float*)d_in[3];
    const float* gbihf      = (const float*)d_in[4];
    const float* gbhhf      = (const float*)d_in[5];
    const float* gWihb      = (const float*)d_in[6];
    const float* gWhhb      = (const float*)d_in[7];
    const float* gbihb      = (const float*)d_in[8];
    const float* gbhhb      = (const float*)d_in[9];
    const float* hW         = (const float*)d_in[10];
    const float* hb         = (const float*)d_in[11];
    const float* tW         = (const float*)d_in[12];
    const float* tb         = (const float*)d_in[13];
    const float* trans      = (const float*)d_in[14];
    const float* lW         = (const float*)d_in[15];
    const float* lb         = (const float*)d_in[16];
    const int*   masks      = (const int*)d_in[17];
    const int*   lens       = (const int*)d_in[18];
    const int*   labels     = (const int*)d_in[19];

    char* wsb = (char*)d_ws;
    __hip_bfloat16* gi    = (__hip_bfloat16*)(wsb + OFF_GI);
    __hip_bfloat16* ctxb  = (__hip_bfloat16*)(wsb + OFF_CTXB);
    __hip_bfloat16* xbf   = (__hip_bfloat16*)(wsb + OFF_XBF);
    __hip_bfloat16* wihB  = (__hip_bfloat16*)(wsb + OFF_WIHB);
    __hip_bfloat16* whhB  = (__hip_bfloat16*)(wsb + OFF_WHHB);
    float* biasAll        = (float*)(wsb + OFF_BIAS);
    float* W2             = (float*)(wsb + OFF_W2);
    float* b2             = (float*)(wsb + OFF_B2);
    int* beg              = (int*)(wsb + OFF_BEG);
    int* tn               = (int*)(wsb + OFF_TN);
    float* scores         = (float*)(wsb + OFF_SCORES);
    float* fk             = (float*)(wsb + OFF_FK);
    float* alphas         = (float*)(wsb + OFF_AL);
    float* sp             = (float*)(wsb + OFF_SP);
    float* spsum          = (float*)(wsb + OFF_SPSUM);
    float* sv             = (float*)(wsb + OFF_SV);

    hipLaunchKernelGGL(k_zero, dim3(1024), dim3(256), 0, stream, (float4*)(wsb + OFF_CTXB));
    hipLaunchKernelGGL(k_prep_x, dim3((MTOT * KP + 255) / 256), dim3(256), 0, stream,
                       sents, mask_table, masks, xbf);
    hipLaunchKernelGGL(k_prep_wihB, dim3((N2 * KP + 255) / 256), dim3(256), 0, stream,
                       gWihf, gWihb, gbihf, gbihb, wihB, biasAll);
    hipLaunchKernelGGL(k_prep_whhB, dim3((2 * G3 * HDIM + 255) / 256), dim3(256), 0, stream,
                       gWhhf, gWhhb, whhB);
    hipLaunchKernelGGL(k_prep_w2, dim3((16 * HH + 255) / 256), dim3(256), 0, stream,
                       hW, hb, tW, tb, W2, b2);
    hipLaunchKernelGGL(k_prep_bt, dim3(1), dim3(128), 0, stream, masks, beg, tn);

    hipLaunchKernelGGL(k_mfma_gi, dim3(N2 / 64, MTOT / 64), dim3(256), 0, stream,
                       (const short*)xbf, (const short*)wihB, biasAll, gi);
    hipLaunchKernelGGL(k_gru_mfma, dim3(16), dim3(512), 0, stream,
                       gi, (const short*)whhB, gbhhf, gbhhb, lens, masks, beg, tn, ctxb);
    hipLaunchKernelGGL(k_fk, dim3(MTOT * 16 / 256), dim3(256), 0, stream,
                       ctxb, W2, b2, fk);
    hipLaunchKernelGGL(k_crf, dim3(32), dim3(64), 0, stream, fk, trans, lens, alphas, sp, spsum);
    hipLaunchKernelGGL(k_pool, dim3(BB), dim3(256), 0, stream, ctxb, sp, spsum, sv);
    hipLaunchKernelGGL(k_scores, dim3(BB), dim3(256), 0, stream, sv, lW, lb, scores);
    hipLaunchKernelGGL(k_final2, dim3(1), dim3(128), 0, stream, scores, labels, (float*)d_out);
}